// Round 8
// baseline (4696.987 us; speedup 1.0000x reference)
//
#include <hip/hip_runtime.h>
#include <hip/hip_cooperative_groups.h>
namespace cg = cooperative_groups;

constexpr int BB = 4, TT = 12, NN = 20000, FIN = 2;
constexpr int HID = 64, OUTC = 5;
constexpr int FIL = 32;
constexpr int T1n = 10, T2n = 8;
constexpr int EE = 320000;
constexpr long ROWS = (long)T1n * NN;  // 200000 rows per batch

typedef __attribute__((ext_vector_type(8))) short short8v;  // 8 bf16 (4 VGPRs)
typedef __attribute__((ext_vector_type(4))) float f32x4;

struct EdgeP { int c; float w; };  // fused CSR record (8B)

// ---------------- workspace layout (bytes) ----------------
constexpr size_t SZ_B   = (size_t)ROWS * 64 * 2;             // 25,600,000 bf16 slab
constexpr size_t SZ_H3P = (size_t)T2n * BB * NN * 8 * 4;     // 20,480,000 (rows padded 5->8)
constexpr size_t O_XB  = 0;
constexpr size_t O_T1B = SZ_B;
constexpr size_t O_T2B = 2 * SZ_B;
constexpr size_t O_H2B = 3 * SZ_B;                            // bf16 now
constexpr size_t O_H3  = O_H2B + SZ_B;
constexpr size_t O_PX  = O_H3 + SZ_H3P;
constexpr size_t O_BNS = O_PX + SZ_H3P;
constexpr size_t O_BNH = O_BNS + 80000;
constexpr size_t O_DEG = O_BNH + 80000;
constexpr size_t O_IND = O_DEG + 80000;
constexpr size_t O_CUR = O_IND + 80000;
constexpr size_t O_DNV = O_CUR + 80000;
constexpr size_t O_RP  = O_DNV + 80000;
constexpr size_t O_EPK = O_RP + 80128;
constexpr size_t O_LG  = O_EPK + (size_t)EE * 8;
constexpr size_t O_WP  = O_LG + 2560000;
constexpr size_t WS_NEED = O_WP + 24576;
constexpr size_t SZ_H = (size_t)BB * NN * FIL * 4;            // 10,240,000 (GRU state)

// ---------------- bf16 helpers ----------------
__device__ __forceinline__ float bf2f(unsigned short u) {
  union { unsigned i; float f; } x; x.i = ((unsigned)u) << 16; return x.f;
}
__device__ __forceinline__ unsigned short f2bf(float f) {
  union { float f; unsigned i; } x; x.f = f;
  unsigned r = x.i + 0x7FFFu + ((x.i >> 16) & 1u);
  return (unsigned short)(r >> 16);
}
__device__ __forceinline__ float lo_bf(unsigned u) {
  union { unsigned i; float f; } x; x.i = u << 16; return x.f;
}
__device__ __forceinline__ float hi_bf(unsigned u) {
  union { unsigned i; float f; } x; x.i = u & 0xffff0000u; return x.f;
}

// ---------------- XCD-chunked bijective block swizzle (m204) ----------------
__device__ __forceinline__ unsigned swz8(unsigned orig, unsigned nwg) {
  unsigned q = nwg >> 3, r = nwg & 7;
  unsigned xcd = orig & 7, off = orig >> 3;
  unsigned base = (xcd < r) ? xcd * (q + 1) : r * (q + 1) + (xcd - r) * q;
  return base + off;
}

// ---------------- graph preprocessing ----------------
__global__ void __launch_bounds__(256) k_edge_count(const int* __restrict__ ei, int E,
                                                    float* __restrict__ degf, int* __restrict__ indeg) {
  int e = blockIdx.x * 256 + threadIdx.x;
  if (e >= E) return;
  int s = ei[e], d = ei[E + e];
  if (s != d) {
    atomicAdd(&degf[s], 1.0f);
    atomicAdd(&indeg[d], 1);
  }
}

__global__ void __launch_bounds__(256) k_dinv(const float* __restrict__ degf, float* __restrict__ dinv) {
  int n = blockIdx.x * 256 + threadIdx.x;
  if (n >= NN) return;
  float d = degf[n];
  dinv[n] = d > 0.f ? rsqrtf(d) : 0.f;
}

__global__ void __launch_bounds__(1024) k_scan(const int* __restrict__ indeg, int* __restrict__ rowptr) {
  __shared__ int part[1024];
  const int chunk = (NN + 1023) / 1024;
  int t = threadIdx.x;
  int beg = t * chunk, end = min(beg + chunk, NN);
  int s = 0;
  for (int i = beg; i < end; ++i) s += indeg[i];
  part[t] = s;
  __syncthreads();
  if (t == 0) {
    int run = 0;
    for (int i = 0; i < 1024; ++i) { int v = part[i]; part[i] = run; run += v; }
    rowptr[NN] = run;
  }
  __syncthreads();
  int run = part[t];
  for (int i = beg; i < end; ++i) { rowptr[i] = run; run += indeg[i]; }
}

__global__ void __launch_bounds__(256) k_fill(const int* __restrict__ ei, int E,
                                              const float* __restrict__ dinv,
                                              const int* __restrict__ rowptr,
                                              int* __restrict__ cursor,
                                              EdgeP* __restrict__ epk) {
  int e = blockIdx.x * 256 + threadIdx.x;
  if (e >= E) return;
  int s = ei[e], d = ei[E + e];
  if (s != d) {
    int p = atomicAdd(&cursor[d], 1);
    EdgeP ep; ep.c = s; ep.w = -dinv[s] * dinv[d];
    epk[rowptr[d] + p] = ep;
  }
}

// ---------------- cheb weight pack into MFMA B-fragment order (bf16) ----------------
__global__ void __launch_bounds__(256) k_wpack(const float* __restrict__ W, unsigned short* __restrict__ Wp) {
  int id = blockIdx.x * 256 + threadIdx.x;
  int f = id >> 6, l = id & 63;
  int kk = f >> 2, jt = f & 3;
  int kcheb = kk >> 1;
  int cout = jt * 16 + (l & 15);
#pragma unroll
  for (int e = 0; e < 8; ++e) {
    int cin = (kk & 1) * 32 + (l >> 4) * 8 + e;
    Wp[(size_t)f * 512 + l * 8 + e] = f2bf(W[(size_t)kcheb * 4096 + cin * 64 + cout]);
  }
}

// ---------------- temporal conv 1: (B,T,N,2) -> per-b bf16 (10,N,64) ----------------
__global__ void __launch_bounds__(256) k_tc1(const float* __restrict__ x, const float* __restrict__ W,
                                             const float* __restrict__ Bv, unsigned short* __restrict__ out, int b) {
  __shared__ float ws[1152];
  __shared__ float bs[192];
  for (int i = threadIdx.x; i < 1152; i += 256) ws[i] = W[i];
  for (int i = threadIdx.x; i < 192; i += 256) bs[i] = Bv[i];
  __syncthreads();
  long tid = (long)blockIdx.x * 256 + threadIdx.x;
  if (tid >= ROWS * 64) return;
  int co = (int)(tid & 63);
  int n  = (int)((tid >> 6) % NN);
  int to = (int)(tid / (64L * NN));
  float aP = bs[co], aQ = bs[64 + co], aR = bs[128 + co];
#pragma unroll
  for (int k = 0; k < 3; ++k) {
#pragma unroll
    for (int ci = 0; ci < 2; ++ci) {
      float xv = x[(((long)b * TT + to + k) * NN + n) * FIN + ci];
      int wi = (k * 2 + ci) * 64 + co;
      aP = fmaf(xv, ws[wi], aP);
      aQ = fmaf(xv, ws[384 + wi], aQ);
      aR = fmaf(xv, ws[768 + wi], aR);
    }
  }
  float sq = 1.f / (1.f + expf(-aQ));
  out[tid] = f2bf(fmaxf(aP * sq + aR, 0.f));
}

// ---------------- bf16 CSR propagation, edge-parallel (8 edges in flight) ----------------
__global__ void __launch_bounds__(256) k_prop_bf(const unsigned short* __restrict__ v,
                                                 unsigned short* __restrict__ out,
                                                 const unsigned short* __restrict__ xin,
                                                 const int* __restrict__ rowptr,
                                                 const EdgeP* __restrict__ epk) {
  unsigned bid = swz8(blockIdx.x, gridDim.x);
  long tid = (long)bid * 256 + threadIdx.x;
  long ng = tid >> 6;
  if (ng >= ROWS) return;
  int lane = threadIdx.x & 63;
  int eq = lane >> 3, cl = lane & 7;
  int s = (int)(ng / NN);
  int n = (int)(ng % NN);
  n = __builtin_amdgcn_readfirstlane(n);
  s = __builtin_amdgcn_readfirstlane(s);
  int beg = rowptr[n], end = rowptr[n + 1];
  const unsigned short* vs = v + (long)s * NN * 64;
  float acc[8] = {0.f, 0.f, 0.f, 0.f, 0.f, 0.f, 0.f, 0.f};
  for (int e0 = beg; e0 < end; e0 += 8) {
    int e = e0 + eq;
    int ec = min(e, end - 1);
    EdgeP ep = epk[ec];
    float w = (e < end) ? ep.w : 0.f;
    const unsigned* a = (const unsigned*)(vs + (((long)ep.c) << 6) + cl * 8);
    unsigned u0 = a[0], u1 = a[1], u2 = a[2], u3 = a[3];
    acc[0] = fmaf(w, lo_bf(u0), acc[0]); acc[1] = fmaf(w, hi_bf(u0), acc[1]);
    acc[2] = fmaf(w, lo_bf(u1), acc[2]); acc[3] = fmaf(w, hi_bf(u1), acc[3]);
    acc[4] = fmaf(w, lo_bf(u2), acc[4]); acc[5] = fmaf(w, hi_bf(u2), acc[5]);
    acc[6] = fmaf(w, lo_bf(u3), acc[6]); acc[7] = fmaf(w, hi_bf(u3), acc[7]);
  }
#pragma unroll
  for (int k = 0; k < 8; ++k) {
    acc[k] += __shfl_xor(acc[k], 8);
    acc[k] += __shfl_xor(acc[k], 16);
    acc[k] += __shfl_xor(acc[k], 32);
  }
  if (eq == 0) {
    long ob = ng * 64 + cl * 8;
    short8v o;
    if (xin) {
      const unsigned* xi = (const unsigned*)(xin + ob);
#pragma unroll
      for (int k = 0; k < 4; ++k) {
        unsigned u = xi[k];
        o[2 * k]     = (short)f2bf(2.f * acc[2 * k]     - lo_bf(u));
        o[2 * k + 1] = (short)f2bf(2.f * acc[2 * k + 1] - hi_bf(u));
      }
    } else {
#pragma unroll
      for (int k = 0; k < 8; ++k) o[k] = (short)f2bf(acc[k]);
    }
    *(short8v*)(out + ob) = o;
  }
}

// ---------------- Cheb combine via MFMA -> bf16 H2 ----------------
__global__ void __launch_bounds__(256) k_cheb_mfma(const unsigned short* __restrict__ Xb,
                                                   const unsigned short* __restrict__ T1b,
                                                   const unsigned short* __restrict__ T2b,
                                                   const unsigned short* __restrict__ Wp,
                                                   const float* __restrict__ Bv,
                                                   unsigned short* __restrict__ H2b) {
  int wid = threadIdx.x >> 6, lane = threadIdx.x & 63;
  long tile = (long)blockIdx.x * 4 + wid;
  if (tile >= ROWS / 16) return;
  int r = lane & 15, g = lane >> 4;
  short8v wf[24];
#pragma unroll
  for (int f = 0; f < 24; ++f)
    wf[f] = *(const short8v*)(Wp + (size_t)f * 512 + lane * 8);
  float bias[4];
#pragma unroll
  for (int jt = 0; jt < 4; ++jt) bias[jt] = Bv[jt * 16 + r];
  long rowbase = tile * 16;
  f32x4 acc[4];
#pragma unroll
  for (int jt = 0; jt < 4; ++jt) acc[jt] = (f32x4){0.f, 0.f, 0.f, 0.f};
  const unsigned short* srcs[3] = {Xb, T1b, T2b};
#pragma unroll
  for (int kk = 0; kk < 6; ++kk) {
    const unsigned short* S = srcs[kk >> 1];
    short8v a = *(const short8v*)(S + (rowbase + r) * 64 + (kk & 1) * 32 + g * 8);
#pragma unroll
    for (int jt = 0; jt < 4; ++jt)
      acc[jt] = __builtin_amdgcn_mfma_f32_16x16x32_bf16(a, wf[kk * 4 + jt], acc[jt], 0, 0, 0);
  }
#pragma unroll
  for (int jt = 0; jt < 4; ++jt)
#pragma unroll
    for (int reg = 0; reg < 4; ++reg) {
      int m = 4 * g + reg;
      H2b[(rowbase + m) * 64 + jt * 16 + r] = f2bf(fmaxf(acc[jt][reg] + bias[jt], 0.f));
    }
}

// ---------------- temporal conv 2: per-b bf16 (10,N,64) -> h3[t*4+b][n][8] ----------------
__global__ void __launch_bounds__(256) k_tc2(const unsigned short* __restrict__ h2b, const float* __restrict__ W,
                                             const float* __restrict__ Bv, float* __restrict__ h3, int b) {
  long tid = (long)blockIdx.x * 256 + threadIdx.x;
  if (tid >= (long)T2n * NN) return;
  int t2 = (int)(tid / NN), n = (int)(tid % NN);
  float p[5], q[5], r[5];
#pragma unroll
  for (int co = 0; co < 5; ++co) { p[co] = Bv[co]; q[co] = Bv[5 + co]; r[co] = Bv[10 + co]; }
#pragma unroll
  for (int k = 0; k < 3; ++k) {
    const unsigned short* rowp = h2b + ((long)(t2 + k) * NN + n) * 64;
    for (int c8 = 0; c8 < 8; ++c8) {
      short8v vv = *(const short8v*)(rowp + c8 * 8);
      const float* w = W + ((k * 64) + c8 * 8) * 5;
#pragma unroll
      for (int u = 0; u < 8; ++u) {
        float xv = bf2f((unsigned short)vv[u]);
#pragma unroll
        for (int co = 0; co < 5; ++co) {
          p[co] = fmaf(xv, w[u * 5 + co], p[co]);
          q[co] = fmaf(xv, w[960 + u * 5 + co], q[co]);
          r[co] = fmaf(xv, w[1920 + u * 5 + co], r[co]);
        }
      }
    }
  }
  float o[5];
#pragma unroll
  for (int co = 0; co < 5; ++co) {
    float sq = 1.f / (1.f + expf(-q[co]));
    o[co] = fmaxf(p[co] * sq + r[co], 0.f);
  }
  float4* dst = (float4*)(h3 + ((long)(t2 * 4 + b) * NN + n) * 8);
  dst[0] = make_float4(o[0], o[1], o[2], o[3]);
  dst[1] = make_float4(o[4], 0.f, 0.f, 0.f);
}

// ================= fused tail: BN + PX-prop + 8x GRU + log_softmax =================
__global__ void __launch_bounds__(256) k_tail(
    float* __restrict__ h3, float* __restrict__ PX,
    float* __restrict__ Hp, float* __restrict__ Hn,
    float* __restrict__ Zb, float* __restrict__ HRb,
    const int* __restrict__ rowptr, const EdgeP* __restrict__ epk,
    const float* __restrict__ gwx, const float* __restrict__ gbx,
    const float* __restrict__ gwh, const float* __restrict__ gbh,
    const float* __restrict__ lw, const float* __restrict__ lb,
    const float* __restrict__ gam, const float* __restrict__ bet,
    float* __restrict__ bnS, float* __restrict__ bnH,
    float* __restrict__ lg, float* __restrict__ out) {
  __shared__ float swh1[4096];  // whz0|whz1|whr0|whr1
  __shared__ float swx1[640];   // wxz0|wxz1|wxr0|wxr1
  __shared__ float swh2[2048];  // whh0|whh1
  __shared__ float swx2[320];   // wxh0|wxh1
  __shared__ float sb[96];      // combined biases z|r|h
  __shared__ float slw[32];
  for (int i = threadIdx.x; i < 4096; i += 256) swh1[i] = gwh[i];
  for (int i = threadIdx.x; i < 640; i += 256) swx1[i] = gwx[i];
  for (int i = threadIdx.x; i < 2048; i += 256) swh2[i] = gwh[4096 + i];
  for (int i = threadIdx.x; i < 320; i += 256) swx2[i] = gwx[640 + i];
  if (threadIdx.x < 96) sb[threadIdx.x] = gbx[threadIdx.x] + gbh[threadIdx.x];
  if (threadIdx.x < 32) slw[threadIdx.x] = lw[threadIdx.x];
  const long gbase = (long)blockIdx.x * 256 + threadIdx.x;
  const long gstride = (long)gridDim.x * 256;
  cg::grid_group grid = cg::this_grid();

  // --- phase 0: zero Hp + bn_stats ---
  for (long i = gbase; i < 4L * NN * FIL; i += gstride) Hp[i] = 0.f;
  for (long idx = gbase; idx < 4L * NN; idx += gstride) {
    int q = (int)(idx & 3);
    int n = (int)(idx >> 2);
    float s1 = 0.f, s2 = 0.f;
    for (int t = q * 2; t < q * 2 + 2; ++t)
      for (int b = 0; b < 4; ++b) {
        const float* p = h3 + ((long)(t * 4 + b) * NN + n) * 8;
#pragma unroll
        for (int co = 0; co < 5; ++co) { float v = p[co]; s1 += v; s2 += v * v; }
      }
    s1 += __shfl_xor(s1, 1, 4); s1 += __shfl_xor(s1, 2, 4);
    s2 += __shfl_xor(s2, 1, 4); s2 += __shfl_xor(s2, 2, 4);
    if (q == 0) {
      float mean = s1 * (1.f / 160.f);
      float var = s2 * (1.f / 160.f) - mean * mean;
      float sc = gam[n] * rsqrtf(var + 1e-5f);
      bnS[n] = sc;
      bnH[n] = bet[n] - mean * sc;
    }
  }
  grid.sync();

  // --- phase 1: bn_apply ---
  for (long idx = gbase; idx < 32L * NN * 8; idx += gstride) {
    int n = (int)((idx >> 3) % NN);
    h3[idx] = fmaxf(h3[idx] * bnS[n] + bnH[n], 0.f);
  }
  grid.sync();

  // --- phase 2: PX = prop(h3) (edge-parallel, 8 lanes/node) ---
  for (long idx = gbase; idx < 32L * NN * 8; idx += gstride) {
    long ng = idx >> 3;
    int eq = (int)(idx & 7);
    int s = (int)(ng / NN), n = (int)(ng % NN);
    int beg = rowptr[n], end = rowptr[n + 1];
    const float* src = h3 + (long)s * NN * 8;
    float a0 = 0.f, a1 = 0.f, a2 = 0.f, a3 = 0.f, a4 = 0.f;
    for (int e0 = beg; e0 < end; e0 += 8) {
      int e = e0 + eq;
      int ec = min(e, end - 1);
      EdgeP ep = epk[ec];
      float w = (e < end) ? ep.w : 0.f;
      const float* row = src + ((long)ep.c) * 8;
      float4 v = *(const float4*)row;
      float v4 = row[4];
      a0 = fmaf(w, v.x, a0); a1 = fmaf(w, v.y, a1); a2 = fmaf(w, v.z, a2);
      a3 = fmaf(w, v.w, a3); a4 = fmaf(w, v4, a4);
    }
#pragma unroll
    for (int m = 1; m <= 4; m <<= 1) {
      a0 += __shfl_xor(a0, m); a1 += __shfl_xor(a1, m); a2 += __shfl_xor(a2, m);
      a3 += __shfl_xor(a3, m); a4 += __shfl_xor(a4, m);
    }
    if (eq == 0) {
      float* dst = PX + ng * 8;
      *(float4*)dst = make_float4(a0, a1, a2, a3);
      dst[4] = a4;
    }
  }
  grid.sync();

  // --- 8 GRU steps, 2 phases each ---
  for (int t = 0; t < 8; ++t) {
    float* cur = (t & 1) ? Hn : Hp;
    float* nxt = (t & 1) ? Hp : Hn;
    // phase A: Z, HR
    for (long idx = gbase; idx < 4L * NN * 32; idx += gstride) {
      long ng = idx >> 5;
      int j = (int)(idx & 31);
      int b = (int)(ng / NN), n = (int)(ng % NN);
      long hrow = ng * 32;
      long xrow = ((long)(t * 4 + b) * NN + n) * 8;
      const float* hsrc = cur + (long)b * NN * 32;
      float hv = cur[hrow + j];
      int eq = j >> 3, cl = j & 7;
      int beg = rowptr[n], end = rowptr[n + 1];
      float4 pa = make_float4(0.f, 0.f, 0.f, 0.f);
      for (int e0 = beg; e0 < end; e0 += 4) {
        int e = e0 + eq;
        int ec = min(e, end - 1);
        EdgeP ep = epk[ec];
        float w = (e < end) ? ep.w : 0.f;
        float4 hh = *(const float4*)(hsrc + ((long)ep.c) * 32 + cl * 4);
        pa.x = fmaf(w, hh.x, pa.x); pa.y = fmaf(w, hh.y, pa.y);
        pa.z = fmaf(w, hh.z, pa.z); pa.w = fmaf(w, hh.w, pa.w);
      }
      pa.x += __shfl_xor(pa.x, 8);  pa.y += __shfl_xor(pa.y, 8);
      pa.z += __shfl_xor(pa.z, 8);  pa.w += __shfl_xor(pa.w, 8);
      pa.x += __shfl_xor(pa.x, 16); pa.y += __shfl_xor(pa.y, 16);
      pa.z += __shfl_xor(pa.z, 16); pa.w += __shfl_xor(pa.w, 16);
      float v0 = __shfl(pa.x, j >> 2, 32);
      float v1 = __shfl(pa.y, j >> 2, 32);
      float v2 = __shfl(pa.z, j >> 2, 32);
      float v3 = __shfl(pa.w, j >> 2, 32);
      int pp = j & 3;
      float ph = pp == 0 ? v0 : pp == 1 ? v1 : pp == 2 ? v2 : v3;

      float az = sb[j];
      float ar = sb[32 + j];
#pragma unroll
      for (int ci = 0; ci < 5; ++ci) {
        float xv = h3[xrow + ci], pv = PX[xrow + ci];
        az += xv * swx1[ci * 32 + j] + pv * swx1[160 + ci * 32 + j];
        ar += xv * swx1[320 + ci * 32 + j] + pv * swx1[480 + ci * 32 + j];
      }
#pragma unroll
      for (int ci = 0; ci < 32; ++ci) {
        float hb = __shfl(hv, ci, 32);
        float pb = __shfl(ph, ci, 32);
        az += hb * swh1[ci * 32 + j] + pb * swh1[1024 + ci * 32 + j];
        ar += hb * swh1[2048 + ci * 32 + j] + pb * swh1[3072 + ci * 32 + j];
      }
      float zz = 1.f / (1.f + expf(-az));
      float rr = 1.f / (1.f + expf(-ar));
      Zb[hrow + j] = zz;
      HRb[hrow + j] = hv * rr;
    }
    grid.sync();
    // phase B: Hn, logits
    for (long idx = gbase; idx < 4L * NN * 32; idx += gstride) {
      long ng = idx >> 5;
      int j = (int)(idx & 31);
      int b = (int)(ng / NN), n = (int)(ng % NN);
      long hrow = ng * 32;
      long xrow = ((long)(t * 4 + b) * NN + n) * 8;
      const float* hsrc = HRb + (long)b * NN * 32;
      float hrv = HRb[hrow + j];
      int eq = j >> 3, cl = j & 7;
      int beg = rowptr[n], end = rowptr[n + 1];
      float4 pa = make_float4(0.f, 0.f, 0.f, 0.f);
      for (int e0 = beg; e0 < end; e0 += 4) {
        int e = e0 + eq;
        int ec = min(e, end - 1);
        EdgeP ep = epk[ec];
        float w = (e < end) ? ep.w : 0.f;
        float4 hh = *(const float4*)(hsrc + ((long)ep.c) * 32 + cl * 4);
        pa.x = fmaf(w, hh.x, pa.x); pa.y = fmaf(w, hh.y, pa.y);
        pa.z = fmaf(w, hh.z, pa.z); pa.w = fmaf(w, hh.w, pa.w);
      }
      pa.x += __shfl_xor(pa.x, 8);  pa.y += __shfl_xor(pa.y, 8);
      pa.z += __shfl_xor(pa.z, 8);  pa.w += __shfl_xor(pa.w, 8);
      pa.x += __shfl_xor(pa.x, 16); pa.y += __shfl_xor(pa.y, 16);
      pa.z += __shfl_xor(pa.z, 16); pa.w += __shfl_xor(pa.w, 16);
      float v0 = __shfl(pa.x, j >> 2, 32);
      float v1 = __shfl(pa.y, j >> 2, 32);
      float v2 = __shfl(pa.z, j >> 2, 32);
      float v3 = __shfl(pa.w, j >> 2, 32);
      int pp = j & 3;
      float phr = pp == 0 ? v0 : pp == 1 ? v1 : pp == 2 ? v2 : v3;

      float a = sb[64 + j];
#pragma unroll
      for (int ci = 0; ci < 5; ++ci) {
        float xv = h3[xrow + ci], pv = PX[xrow + ci];
        a += xv * swx2[ci * 32 + j] + pv * swx2[160 + ci * 32 + j];
      }
#pragma unroll
      for (int ci = 0; ci < 32; ++ci) {
        float hb = __shfl(hrv, ci, 32);
        float pb = __shfl(phr, ci, 32);
        a += hb * swh2[ci * 32 + j] + pb * swh2[1024 + ci * 32 + j];
      }
      float zz = Zb[hrow + j];
      float hn = zz * cur[hrow + j] + (1.f - zz) * tanhf(a);
      nxt[hrow + j] = hn;
      float c = fmaxf(hn, 0.f) * slw[j];
      c += __shfl_xor(c, 16, 32);
      c += __shfl_xor(c, 8, 32);
      c += __shfl_xor(c, 4, 32);
      c += __shfl_xor(c, 2, 32);
      c += __shfl_xor(c, 1, 32);
      if (j == 0) lg[((long)b * 8 + t) * NN + n] = c + lb[0];
    }
    grid.sync();
  }

  // --- final: log_softmax over the 8 time steps ---
  for (long idx = gbase; idx < 4L * NN; idx += gstride) {
    int b = (int)(idx / NN), n = (int)(idx % NN);
    float l[8];
#pragma unroll
    for (int t = 0; t < 8; ++t) l[t] = lg[((long)b * 8 + t) * NN + n];
    float m = l[0];
#pragma unroll
    for (int t = 1; t < 8; ++t) m = fmaxf(m, l[t]);
    float s = 0.f;
#pragma unroll
    for (int t = 0; t < 8; ++t) s += expf(l[t] - m);
    float lse = m + logf(s);
#pragma unroll
    for (int t = 0; t < 8; ++t) out[((long)b * 8 + t) * NN + n] = l[t] - lse;
  }
}

// ================= fallback discrete kernels (if coop launch unsupported) =================
__global__ void __launch_bounds__(256) k_bn_stats(const float* __restrict__ h3,
                                                  const float* __restrict__ gamma,
                                                  const float* __restrict__ beta,
                                                  float* __restrict__ bnS, float* __restrict__ bnH) {
  long tid = (long)blockIdx.x * 256 + threadIdx.x;
  if (tid >= 4L * NN) return;
  int q = (int)(tid & 3);
  int n = (int)(tid >> 2);
  float s1 = 0.f, s2 = 0.f;
  for (int t = q * 2; t < q * 2 + 2; ++t)
    for (int b = 0; b < 4; ++b) {
      const float* p = h3 + ((long)(t * 4 + b) * NN + n) * 8;
#pragma unroll
      for (int co = 0; co < 5; ++co) { float v = p[co]; s1 += v; s2 += v * v; }
    }
  s1 += __shfl_xor(s1, 1, 4); s1 += __shfl_xor(s1, 2, 4);
  s2 += __shfl_xor(s2, 1, 4); s2 += __shfl_xor(s2, 2, 4);
  if (q == 0) {
    float mean = s1 * (1.f / 160.f);
    float var = s2 * (1.f / 160.f) - mean * mean;
    float sc = gamma[n] * rsqrtf(var + 1e-5f);
    bnS[n] = sc;
    bnH[n] = beta[n] - mean * sc;
  }
}

__global__ void __launch_bounds__(256) k_bn_apply(float* __restrict__ h3,
                                                  const float* __restrict__ bnS,
                                                  const float* __restrict__ bnH) {
  long tid = (long)blockIdx.x * 256 + threadIdx.x;
  if (tid >= 32L * NN * 8) return;
  int n = (int)((tid >> 3) % NN);
  h3[tid] = fmaxf(h3[tid] * bnS[n] + bnH[n], 0.f);
}

__global__ void __launch_bounds__(256) k_prop5(const float* __restrict__ h3, float* __restrict__ PX,
                                               const int* __restrict__ rowptr, const EdgeP* __restrict__ epk) {
  long tid = (long)blockIdx.x * 256 + threadIdx.x;
  long ng = tid >> 3;
  int eq = (int)(tid & 7);
  if (ng >= 32L * NN) return;
  int s = (int)(ng / NN), n = (int)(ng % NN);
  int beg = rowptr[n], end = rowptr[n + 1];
  const float* src = h3 + (long)s * NN * 8;
  float a0 = 0.f, a1 = 0.f, a2 = 0.f, a3 = 0.f, a4 = 0.f;
  for (int e0 = beg; e0 < end; e0 += 8) {
    int e = e0 + eq;
    int ec = min(e, end - 1);
    EdgeP ep = epk[ec];
    float w = (e < end) ? ep.w : 0.f;
    const float* row = src + ((long)ep.c) * 8;
    float4 v = *(const float4*)row;
    float v4 = row[4];
    a0 = fmaf(w, v.x, a0); a1 = fmaf(w, v.y, a1); a2 = fmaf(w, v.z, a2);
    a3 = fmaf(w, v.w, a3); a4 = fmaf(w, v4, a4);
  }
#pragma unroll
  for (int m = 1; m <= 4; m <<= 1) {
    a0 += __shfl_xor(a0, m); a1 += __shfl_xor(a1, m); a2 += __shfl_xor(a2, m);
    a3 += __shfl_xor(a3, m); a4 += __shfl_xor(a4, m);
  }
  if (eq == 0) {
    float* dst = PX + ng * 8;
    *(float4*)dst = make_float4(a0, a1, a2, a3);
    dst[4] = a4;
  }
}

__global__ void __launch_bounds__(256) k_gru1(const float* __restrict__ h3, const float* __restrict__ PX,
                                              const float* __restrict__ Hp,
                                              const int* __restrict__ rowptr, const EdgeP* __restrict__ epk,
                                              const float* __restrict__ gwx, const float* __restrict__ gbx,
                                              const float* __restrict__ gwh, const float* __restrict__ gbh,
                                              float* __restrict__ Z, float* __restrict__ HR, int t) {
  __shared__ float swh[4096];
  __shared__ float swx[640];
  for (int i = threadIdx.x; i < 4096; i += 256) swh[i] = gwh[i];
  for (int i = threadIdx.x; i < 640; i += 256) swx[i] = gwx[i];
  __syncthreads();
  long tid = (long)blockIdx.x * 256 + threadIdx.x;
  long ng = tid >> 5;
  int j = (int)(tid & 31);
  if (ng >= 4L * NN) return;
  int b = (int)(ng / NN), n = (int)(ng % NN);
  long hrow = ng * 32;
  long xrow = ((long)(t * 4 + b) * NN + n) * 8;
  const float* hsrc = Hp + (long)b * NN * 32;
  float hv = Hp[hrow + j];
  int eq = j >> 3, cl = j & 7;
  int beg = rowptr[n], end = rowptr[n + 1];
  float4 pa = make_float4(0.f, 0.f, 0.f, 0.f);
  for (int e0 = beg; e0 < end; e0 += 4) {
    int e = e0 + eq;
    int ec = min(e, end - 1);
    EdgeP ep = epk[ec];
    float w = (e < end) ? ep.w : 0.f;
    float4 hh = *(const float4*)(hsrc + ((long)ep.c) * 32 + cl * 4);
    pa.x = fmaf(w, hh.x, pa.x); pa.y = fmaf(w, hh.y, pa.y);
    pa.z = fmaf(w, hh.z, pa.z); pa.w = fmaf(w, hh.w, pa.w);
  }
  pa.x += __shfl_xor(pa.x, 8);  pa.y += __shfl_xor(pa.y, 8);
  pa.z += __shfl_xor(pa.z, 8);  pa.w += __shfl_xor(pa.w, 8);
  pa.x += __shfl_xor(pa.x, 16); pa.y += __shfl_xor(pa.y, 16);
  pa.z += __shfl_xor(pa.z, 16); pa.w += __shfl_xor(pa.w, 16);
  float v0 = __shfl(pa.x, j >> 2, 32);
  float v1 = __shfl(pa.y, j >> 2, 32);
  float v2 = __shfl(pa.z, j >> 2, 32);
  float v3 = __shfl(pa.w, j >> 2, 32);
  int pp = j & 3;
  float ph = pp == 0 ? v0 : pp == 1 ? v1 : pp == 2 ? v2 : v3;
  float az = gbx[j] + gbh[j];
  float ar = gbx[32 + j] + gbh[32 + j];
#pragma unroll
  for (int ci = 0; ci < 5; ++ci) {
    float xv = h3[xrow + ci], pv = PX[xrow + ci];
    az += xv * swx[ci * 32 + j] + pv * swx[160 + ci * 32 + j];
    ar += xv * swx[320 + ci * 32 + j] + pv * swx[480 + ci * 32 + j];
  }
#pragma unroll
  for (int ci = 0; ci < 32; ++ci) {
    float hb = __shfl(hv, ci, 32);
    float pb = __shfl(ph, ci, 32);
    az += hb * swh[ci * 32 + j] + pb * swh[1024 + ci * 32 + j];
    ar += hb * swh[2048 + ci * 32 + j] + pb * swh[3072 + ci * 32 + j];
  }
  float zz = 1.f / (1.f + expf(-az));
  float rr = 1.f / (1.f + expf(-ar));
  Z[hrow + j] = zz;
  HR[hrow + j] = hv * rr;
}

__global__ void __launch_bounds__(256) k_gru2(const float* __restrict__ h3, const float* __restrict__ PX,
                                              const float* __restrict__ Hp, const float* __restrict__ Z,
                                              const float* __restrict__ HR,
                                              const int* __restrict__ rowptr, const EdgeP* __restrict__ epk,
                                              const float* __restrict__ gwx, const float* __restrict__ gbx,
                                              const float* __restrict__ gwh, const float* __restrict__ gbh,
                                              const float* __restrict__ lw, const float* __restrict__ lb,
                                              float* __restrict__ Hn, float* __restrict__ logits, int t) {
  __shared__ float swh[2048];
  __shared__ float swx[320];
  for (int i = threadIdx.x; i < 2048; i += 256) swh[i] = gwh[4096 + i];
  for (int i = threadIdx.x; i < 320; i += 256) swx[i] = gwx[640 + i];
  __syncthreads();
  long tid = (long)blockIdx.x * 256 + threadIdx.x;
  long ng = tid >> 5;
  int j = (int)(tid & 31);
  if (ng >= 4L * NN) return;
  int b = (int)(ng / NN), n = (int)(ng % NN);
  long hrow = ng * 32;
  long xrow = ((long)(t * 4 + b) * NN + n) * 8;
  const float* hsrc = HR + (long)b * NN * 32;
  float hrv = HR[hrow + j];
  int eq = j >> 3, cl = j & 7;
  int beg = rowptr[n], end = rowptr[n + 1];
  float4 pa = make_float4(0.f, 0.f, 0.f, 0.f);
  for (int e0 = beg; e0 < end; e0 += 4) {
    int e = e0 + eq;
    int ec = min(e, end - 1);
    EdgeP ep = epk[ec];
    float w = (e < end) ? ep.w : 0.f;
    float4 hh = *(const float4*)(hsrc + ((long)ep.c) * 32 + cl * 4);
    pa.x = fmaf(w, hh.x, pa.x); pa.y = fmaf(w, hh.y, pa.y);
    pa.z = fmaf(w, hh.z, pa.z); pa.w = fmaf(w, hh.w, pa.w);
  }
  pa.x += __shfl_xor(pa.x, 8);  pa.y += __shfl_xor(pa.y, 8);
  pa.z += __shfl_xor(pa.z, 8);  pa.w += __shfl_xor(pa.w, 8);
  pa.x += __shfl_xor(pa.x, 16); pa.y += __shfl_xor(pa.y, 16);
  pa.z += __shfl_xor(pa.z, 16); pa.w += __shfl_xor(pa.w, 16);
  float v0 = __shfl(pa.x, j >> 2, 32);
  float v1 = __shfl(pa.y, j >> 2, 32);
  float v2 = __shfl(pa.z, j >> 2, 32);
  float v3 = __shfl(pa.w, j >> 2, 32);
  int pp = j & 3;
  float phr = pp == 0 ? v0 : pp == 1 ? v1 : pp == 2 ? v2 : v3;
  float a = gbx[64 + j] + gbh[64 + j];
#pragma unroll
  for (int ci = 0; ci < 5; ++ci) {
    float xv = h3[xrow + ci], pv = PX[xrow + ci];
    a += xv * swx[ci * 32 + j] + pv * swx[160 + ci * 32 + j];
  }
#pragma unroll
  for (int ci = 0; ci < 32; ++ci) {
    float hb = __shfl(hrv, ci, 32);
    float pb = __shfl(phr, ci, 32);
    a += hb * swh[ci * 32 + j] + pb * swh[1024 + ci * 32 + j];
  }
  float zz = Z[hrow + j];
  float hn = zz * Hp[hrow + j] + (1.f - zz) * tanhf(a);
  Hn[hrow + j] = hn;
  float c = fmaxf(hn, 0.f) * lw[j];
  c += __shfl_xor(c, 16, 32);
  c += __shfl_xor(c, 8, 32);
  c += __shfl_xor(c, 4, 32);
  c += __shfl_xor(c, 2, 32);
  c += __shfl_xor(c, 1, 32);
  if (j == 0) logits[((long)b * 8 + t) * NN + n] = c + lb[0];
}

__global__ void __launch_bounds__(256) k_logsoftmax(const float* __restrict__ logits, float* __restrict__ out) {
  long tid = (long)blockIdx.x * 256 + threadIdx.x;
  if (tid >= 4L * NN) return;
  int b = (int)(tid / NN), n = (int)(tid % NN);
  float l[8];
#pragma unroll
  for (int t = 0; t < 8; ++t) l[t] = logits[((long)b * 8 + t) * NN + n];
  float m = l[0];
#pragma unroll
  for (int t = 1; t < 8; ++t) m = fmaxf(m, l[t]);
  float s = 0.f;
#pragma unroll
  for (int t = 0; t < 8; ++t) s += expf(l[t] - m);
  float lse = m + logf(s);
#pragma unroll
  for (int t = 0; t < 8; ++t) out[((long)b * 8 + t) * NN + n] = l[t] - lse;
}

// ---------------- host orchestration ----------------
extern "C" void kernel_launch(void* const* d_in, const int* in_sizes, int n_in,
                              void* d_out, int out_size, void* d_ws, size_t ws_size,
                              hipStream_t stream) {
  const float* x     = (const float*)d_in[0];
  const int*   ei    = (const int*)d_in[1];
  const float* tc1w  = (const float*)d_in[2];
  const float* tc1b  = (const float*)d_in[3];
  const float* chebw = (const float*)d_in[4];
  const float* chebb = (const float*)d_in[5];
  const float* tc2w  = (const float*)d_in[6];
  const float* tc2b  = (const float*)d_in[7];
  const float* gam   = (const float*)d_in[8];
  const float* bet   = (const float*)d_in[9];
  const float* gwx   = (const float*)d_in[10];
  const float* gbx   = (const float*)d_in[11];
  const float* gwh   = (const float*)d_in[12];
  const float* gbh   = (const float*)d_in[13];
  const float* lw    = (const float*)d_in[14];
  const float* lb    = (const float*)d_in[15];
  float* out = (float*)d_out;
  int E = in_sizes[1] / 2;
  if (ws_size < WS_NEED) return;

  char* ws = (char*)d_ws;
  unsigned short* Xb  = (unsigned short*)(ws + O_XB);
  unsigned short* T1b = (unsigned short*)(ws + O_T1B);
  unsigned short* T2b = (unsigned short*)(ws + O_T2B);
  unsigned short* H2b = (unsigned short*)(ws + O_H2B);
  float* h3   = (float*)(ws + O_H3);
  float* PX   = (float*)(ws + O_PX);
  float* bnS  = (float*)(ws + O_BNS);
  float* bnH  = (float*)(ws + O_BNH);
  float* degf = (float*)(ws + O_DEG);
  int*   ind  = (int*)(ws + O_IND);
  int*   cur  = (int*)(ws + O_CUR);
  float* dnv  = (float*)(ws + O_DNV);
  int*   rp   = (int*)(ws + O_RP);
  EdgeP* epk  = (EdgeP*)(ws + O_EPK);
  float* lg   = (float*)(ws + O_LG);
  unsigned short* Wp = (unsigned short*)(ws + O_WP);
  float* Hp  = (float*)(ws + O_XB);
  float* Hn  = (float*)(ws + O_XB + SZ_H);
  float* Zb  = (float*)(ws + O_XB + 2 * SZ_H);
  float* HRb = (float*)(ws + O_XB + 3 * SZ_H);

  // --- graph prep + weight pack ---
  hipMemsetAsync(ws + O_DEG, 0, 240000, stream);
  unsigned gE = (unsigned)((E + 255) / 256);
  k_edge_count<<<gE, 256, 0, stream>>>(ei, E, degf, ind);
  k_dinv<<<(NN + 255) / 256, 256, 0, stream>>>(degf, dnv);
  k_scan<<<1, 1024, 0, stream>>>(ind, rp);
  k_fill<<<gE, 256, 0, stream>>>(ei, E, dnv, rp, cur, epk);
  k_wpack<<<6, 256, 0, stream>>>(chebw, Wp);

  // --- per-batch STConv pipeline ---
  unsigned g64 = (unsigned)((ROWS * 64 + 255) / 256);  // 50000
  for (int b = 0; b < 4; ++b) {
    k_tc1<<<g64, 256, 0, stream>>>(x, tc1w, tc1b, Xb, b);
    k_prop_bf<<<g64, 256, 0, stream>>>(Xb, T1b, nullptr, rp, epk);
    k_prop_bf<<<g64, 256, 0, stream>>>(T1b, T2b, Xb, rp, epk);
    k_cheb_mfma<<<(unsigned)(ROWS / 16 / 4), 256, 0, stream>>>(Xb, T1b, T2b, Wp, chebb, H2b);
    k_tc2<<<(unsigned)(((long)T2n * NN + 255) / 256), 256, 0, stream>>>(H2b, tc2w, tc2b, h3, b);
  }

  // --- fused tail (cooperative); fallback to discrete kernels if unsupported ---
  void* gargs[] = {
    (void*)&h3, (void*)&PX, (void*)&Hp, (void*)&Hn, (void*)&Zb, (void*)&HRb,
    (void*)&rp, (void*)&epk, (void*)&gwx, (void*)&gbx, (void*)&gwh, (void*)&gbh,
    (void*)&lw, (void*)&lb, (void*)&gam, (void*)&bet, (void*)&bnS, (void*)&bnH,
    (void*)&lg, (void*)&out
  };
  hipError_t ce = hipLaunchCooperativeKernel((void*)k_tail, dim3(1024), dim3(256),
                                             gargs, 0, stream);
  if (ce != hipSuccess) {
    k_bn_stats<<<(4 * NN + 255) / 256, 256, 0, stream>>>(h3, gam, bet, bnS, bnH);
    k_bn_apply<<<(unsigned)((32L * NN * 8 + 255) / 256), 256, 0, stream>>>(h3, bnS, bnH);
    k_prop5<<<(unsigned)((32L * NN * 8 + 255) / 256), 256, 0, stream>>>(h3, PX, rp, epk);
    hipMemsetAsync(Hp, 0, SZ_H, stream);
    float* hp = Hp;
    float* hn = Hn;
    unsigned gG = (unsigned)((4L * NN * 32 + 255) / 256);
    for (int t = 0; t < 8; ++t) {
      k_gru1<<<gG, 256, 0, stream>>>(h3, PX, hp, rp, epk, gwx, gbx, gwh, gbh, Zb, HRb, t);
      k_gru2<<<gG, 256, 0, stream>>>(h3, PX, hp, Zb, HRb, rp, epk, gwx, gbx, gwh, gbh,
                                     lw, lb, hn, lg, t);
      float* tmp = hp; hp = hn; hn = tmp;
    }
    unsigned gN = (unsigned)((4L * NN + 255) / 256);
    k_logsoftmax<<<gN, 256, 0, stream>>>(lg, out);
  }
}

// Round 10
// 2348.997 us; speedup vs baseline: 1.9996x; 1.9996x over previous
//
#include <hip/hip_runtime.h>

constexpr int BB = 4, TT = 12, NN = 20000, FIN = 2;
constexpr int HID = 64, OUTC = 5;
constexpr int FIL = 32;
constexpr int T1n = 10, T2n = 8;
constexpr int EE = 320000;
constexpr long ROWS = (long)T1n * NN;  // 200000 rows per batch

typedef __attribute__((ext_vector_type(8))) short short8v;  // 8 bf16 (4 VGPRs)
typedef __attribute__((ext_vector_type(4))) float f32x4;

struct EdgeP { int c; float w; };  // fused CSR record (8B)

// ---------------- workspace layout (bytes) ----------------
constexpr size_t SZ_B   = (size_t)ROWS * 64 * 2;             // 25,600,000 bf16 slab
constexpr size_t SZ_H3P = (size_t)T2n * BB * NN * 8 * 4;     // 20,480,000 (rows padded 5->8)
constexpr size_t O_XB  = 0;
constexpr size_t O_T1B = SZ_B;
constexpr size_t O_T2B = 2 * SZ_B;
constexpr size_t O_H2B = 3 * SZ_B;                            // bf16
constexpr size_t O_H3  = O_H2B + SZ_B;
constexpr size_t O_PX  = O_H3 + SZ_H3P;
constexpr size_t O_BNS = O_PX + SZ_H3P;
constexpr size_t O_BNH = O_BNS + 80000;
constexpr size_t O_DEG = O_BNH + 80000;
constexpr size_t O_IND = O_DEG + 80000;
constexpr size_t O_CUR = O_IND + 80000;
constexpr size_t O_DNV = O_CUR + 80000;
constexpr size_t O_RP  = O_DNV + 80000;
constexpr size_t O_EPK = O_RP + 80128;
constexpr size_t O_LG  = O_EPK + (size_t)EE * 8;
constexpr size_t O_WP  = O_LG + 2560000;
constexpr size_t WS_NEED = O_WP + 24576;
constexpr size_t SZ_H = (size_t)BB * NN * FIL * 4;            // 10,240,000 (GRU state)

// ---------------- bf16 helpers ----------------
__device__ __forceinline__ float bf2f(unsigned short u) {
  union { unsigned i; float f; } x; x.i = ((unsigned)u) << 16; return x.f;
}
__device__ __forceinline__ unsigned short f2bf(float f) {
  union { float f; unsigned i; } x; x.f = f;
  unsigned r = x.i + 0x7FFFu + ((x.i >> 16) & 1u);
  return (unsigned short)(r >> 16);
}
__device__ __forceinline__ float lo_bf(unsigned u) {
  union { unsigned i; float f; } x; x.i = u << 16; return x.f;
}
__device__ __forceinline__ float hi_bf(unsigned u) {
  union { unsigned i; float f; } x; x.i = u & 0xffff0000u; return x.f;
}

// ---------------- XCD-chunked bijective block swizzle (m204) ----------------
__device__ __forceinline__ unsigned swz8(unsigned orig, unsigned nwg) {
  unsigned q = nwg >> 3, r = nwg & 7;
  unsigned xcd = orig & 7, off = orig >> 3;
  unsigned base = (xcd < r) ? xcd * (q + 1) : r * (q + 1) + (xcd - r) * q;
  return base + off;
}

// ---------------- graph preprocessing ----------------
__global__ void __launch_bounds__(256) k_edge_count(const int* __restrict__ ei, int E,
                                                    float* __restrict__ degf, int* __restrict__ indeg) {
  int e = blockIdx.x * 256 + threadIdx.x;
  if (e >= E) return;
  int s = ei[e], d = ei[E + e];
  if (s != d) {
    atomicAdd(&degf[s], 1.0f);
    atomicAdd(&indeg[d], 1);
  }
}

__global__ void __launch_bounds__(256) k_dinv(const float* __restrict__ degf, float* __restrict__ dinv) {
  int n = blockIdx.x * 256 + threadIdx.x;
  if (n >= NN) return;
  float d = degf[n];
  dinv[n] = d > 0.f ? rsqrtf(d) : 0.f;
}

__global__ void __launch_bounds__(1024) k_scan(const int* __restrict__ indeg, int* __restrict__ rowptr) {
  __shared__ int part[1024];
  const int chunk = (NN + 1023) / 1024;
  int t = threadIdx.x;
  int beg = t * chunk, end = min(beg + chunk, NN);
  int s = 0;
  for (int i = beg; i < end; ++i) s += indeg[i];
  part[t] = s;
  __syncthreads();
  if (t == 0) {
    int run = 0;
    for (int i = 0; i < 1024; ++i) { int v = part[i]; part[i] = run; run += v; }
    rowptr[NN] = run;
  }
  __syncthreads();
  int run = part[t];
  for (int i = beg; i < end; ++i) { rowptr[i] = run; run += indeg[i]; }
}

__global__ void __launch_bounds__(256) k_fill(const int* __restrict__ ei, int E,
                                              const float* __restrict__ dinv,
                                              const int* __restrict__ rowptr,
                                              int* __restrict__ cursor,
                                              EdgeP* __restrict__ epk) {
  int e = blockIdx.x * 256 + threadIdx.x;
  if (e >= E) return;
  int s = ei[e], d = ei[E + e];
  if (s != d) {
    int p = atomicAdd(&cursor[d], 1);
    EdgeP ep; ep.c = s; ep.w = -dinv[s] * dinv[d];
    epk[rowptr[d] + p] = ep;
  }
}

// ---------------- cheb weight pack into MFMA B-fragment order (bf16) ----------------
__global__ void __launch_bounds__(256) k_wpack(const float* __restrict__ W, unsigned short* __restrict__ Wp) {
  int id = blockIdx.x * 256 + threadIdx.x;
  int f = id >> 6, l = id & 63;
  int kk = f >> 2, jt = f & 3;
  int kcheb = kk >> 1;
  int cout = jt * 16 + (l & 15);
#pragma unroll
  for (int e = 0; e < 8; ++e) {
    int cin = (kk & 1) * 32 + (l >> 4) * 8 + e;
    Wp[(size_t)f * 512 + l * 8 + e] = f2bf(W[(size_t)kcheb * 4096 + cin * 64 + cout]);
  }
}

// ---------------- temporal conv 1: (B,T,N,2) -> per-b bf16 (10,N,64) ----------------
__global__ void __launch_bounds__(256) k_tc1(const float* __restrict__ x, const float* __restrict__ W,
                                             const float* __restrict__ Bv, unsigned short* __restrict__ out, int b) {
  __shared__ float ws[1152];
  __shared__ float bs[192];
  for (int i = threadIdx.x; i < 1152; i += 256) ws[i] = W[i];
  for (int i = threadIdx.x; i < 192; i += 256) bs[i] = Bv[i];
  __syncthreads();
  long tid = (long)blockIdx.x * 256 + threadIdx.x;
  if (tid >= ROWS * 64) return;
  int co = (int)(tid & 63);
  int n  = (int)((tid >> 6) % NN);
  int to = (int)(tid / (64L * NN));
  float aP = bs[co], aQ = bs[64 + co], aR = bs[128 + co];
#pragma unroll
  for (int k = 0; k < 3; ++k) {
#pragma unroll
    for (int ci = 0; ci < 2; ++ci) {
      float xv = x[(((long)b * TT + to + k) * NN + n) * FIN + ci];
      int wi = (k * 2 + ci) * 64 + co;
      aP = fmaf(xv, ws[wi], aP);
      aQ = fmaf(xv, ws[384 + wi], aQ);
      aR = fmaf(xv, ws[768 + wi], aR);
    }
  }
  float sq = 1.f / (1.f + expf(-aQ));
  out[tid] = f2bf(fmaxf(aP * sq + aR, 0.f));
}

// ---------------- bf16 CSR propagation, edge-parallel (8 edges in flight) ----------------
__global__ void __launch_bounds__(256) k_prop_bf(const unsigned short* __restrict__ v,
                                                 unsigned short* __restrict__ out,
                                                 const unsigned short* __restrict__ xin,
                                                 const int* __restrict__ rowptr,
                                                 const EdgeP* __restrict__ epk) {
  unsigned bid = swz8(blockIdx.x, gridDim.x);
  long tid = (long)bid * 256 + threadIdx.x;
  long ng = tid >> 6;
  if (ng >= ROWS) return;
  int lane = threadIdx.x & 63;
  int eq = lane >> 3, cl = lane & 7;
  int s = (int)(ng / NN);
  int n = (int)(ng % NN);
  n = __builtin_amdgcn_readfirstlane(n);
  s = __builtin_amdgcn_readfirstlane(s);
  int beg = rowptr[n], end = rowptr[n + 1];
  const unsigned short* vs = v + (long)s * NN * 64;
  float acc[8] = {0.f, 0.f, 0.f, 0.f, 0.f, 0.f, 0.f, 0.f};
  for (int e0 = beg; e0 < end; e0 += 8) {
    int e = e0 + eq;
    int ec = min(e, end - 1);
    EdgeP ep = epk[ec];
    float w = (e < end) ? ep.w : 0.f;
    const unsigned* a = (const unsigned*)(vs + (((long)ep.c) << 6) + cl * 8);
    unsigned u0 = a[0], u1 = a[1], u2 = a[2], u3 = a[3];
    acc[0] = fmaf(w, lo_bf(u0), acc[0]); acc[1] = fmaf(w, hi_bf(u0), acc[1]);
    acc[2] = fmaf(w, lo_bf(u1), acc[2]); acc[3] = fmaf(w, hi_bf(u1), acc[3]);
    acc[4] = fmaf(w, lo_bf(u2), acc[4]); acc[5] = fmaf(w, hi_bf(u2), acc[5]);
    acc[6] = fmaf(w, lo_bf(u3), acc[6]); acc[7] = fmaf(w, hi_bf(u3), acc[7]);
  }
#pragma unroll
  for (int k = 0; k < 8; ++k) {
    acc[k] += __shfl_xor(acc[k], 8);
    acc[k] += __shfl_xor(acc[k], 16);
    acc[k] += __shfl_xor(acc[k], 32);
  }
  if (eq == 0) {
    long ob = ng * 64 + cl * 8;
    short8v o;
    if (xin) {
      const unsigned* xi = (const unsigned*)(xin + ob);
#pragma unroll
      for (int k = 0; k < 4; ++k) {
        unsigned u = xi[k];
        o[2 * k]     = (short)f2bf(2.f * acc[2 * k]     - lo_bf(u));
        o[2 * k + 1] = (short)f2bf(2.f * acc[2 * k + 1] - hi_bf(u));
      }
    } else {
#pragma unroll
      for (int k = 0; k < 8; ++k) o[k] = (short)f2bf(acc[k]);
    }
    *(short8v*)(out + ob) = o;
  }
}

// ---------------- Cheb combine via MFMA -> bf16 H2 ----------------
__global__ void __launch_bounds__(256) k_cheb_mfma(const unsigned short* __restrict__ Xb,
                                                   const unsigned short* __restrict__ T1b,
                                                   const unsigned short* __restrict__ T2b,
                                                   const unsigned short* __restrict__ Wp,
                                                   const float* __restrict__ Bv,
                                                   unsigned short* __restrict__ H2b) {
  int wid = threadIdx.x >> 6, lane = threadIdx.x & 63;
  long tile = (long)blockIdx.x * 4 + wid;
  if (tile >= ROWS / 16) return;
  int r = lane & 15, g = lane >> 4;
  short8v wf[24];
#pragma unroll
  for (int f = 0; f < 24; ++f)
    wf[f] = *(const short8v*)(Wp + (size_t)f * 512 + lane * 8);
  float bias[4];
#pragma unroll
  for (int jt = 0; jt < 4; ++jt) bias[jt] = Bv[jt * 16 + r];
  long rowbase = tile * 16;
  f32x4 acc[4];
#pragma unroll
  for (int jt = 0; jt < 4; ++jt) acc[jt] = (f32x4){0.f, 0.f, 0.f, 0.f};
  const unsigned short* srcs[3] = {Xb, T1b, T2b};
#pragma unroll
  for (int kk = 0; kk < 6; ++kk) {
    const unsigned short* S = srcs[kk >> 1];
    short8v a = *(const short8v*)(S + (rowbase + r) * 64 + (kk & 1) * 32 + g * 8);
#pragma unroll
    for (int jt = 0; jt < 4; ++jt)
      acc[jt] = __builtin_amdgcn_mfma_f32_16x16x32_bf16(a, wf[kk * 4 + jt], acc[jt], 0, 0, 0);
  }
#pragma unroll
  for (int jt = 0; jt < 4; ++jt)
#pragma unroll
    for (int reg = 0; reg < 4; ++reg) {
      int m = 4 * g + reg;
      H2b[(rowbase + m) * 64 + jt * 16 + r] = f2bf(fmaxf(acc[jt][reg] + bias[jt], 0.f));
    }
}

// ---------------- temporal conv 2: per-b bf16 (10,N,64) -> h3[t*4+b][n][8] ----------------
__global__ void __launch_bounds__(256) k_tc2(const unsigned short* __restrict__ h2b, const float* __restrict__ W,
                                             const float* __restrict__ Bv, float* __restrict__ h3, int b) {
  long tid = (long)blockIdx.x * 256 + threadIdx.x;
  if (tid >= (long)T2n * NN) return;
  int t2 = (int)(tid / NN), n = (int)(tid % NN);
  float p[5], q[5], r[5];
#pragma unroll
  for (int co = 0; co < 5; ++co) { p[co] = Bv[co]; q[co] = Bv[5 + co]; r[co] = Bv[10 + co]; }
#pragma unroll
  for (int k = 0; k < 3; ++k) {
    const unsigned short* rowp = h2b + ((long)(t2 + k) * NN + n) * 64;
    for (int c8 = 0; c8 < 8; ++c8) {
      short8v vv = *(const short8v*)(rowp + c8 * 8);
      const float* w = W + ((k * 64) + c8 * 8) * 5;
#pragma unroll
      for (int u = 0; u < 8; ++u) {
        float xv = bf2f((unsigned short)vv[u]);
#pragma unroll
        for (int co = 0; co < 5; ++co) {
          p[co] = fmaf(xv, w[u * 5 + co], p[co]);
          q[co] = fmaf(xv, w[960 + u * 5 + co], q[co]);
          r[co] = fmaf(xv, w[1920 + u * 5 + co], r[co]);
        }
      }
    }
  }
  float o[5];
#pragma unroll
  for (int co = 0; co < 5; ++co) {
    float sq = 1.f / (1.f + expf(-q[co]));
    o[co] = fmaxf(p[co] * sq + r[co], 0.f);
  }
  float4* dst = (float4*)(h3 + ((long)(t2 * 4 + b) * NN + n) * 8);
  dst[0] = make_float4(o[0], o[1], o[2], o[3]);
  dst[1] = make_float4(o[4], 0.f, 0.f, 0.f);
}

// ---------------- BatchNorm (padded rows of 8) ----------------
__global__ void __launch_bounds__(256) k_bn_stats(const float* __restrict__ h3,
                                                  const float* __restrict__ gamma,
                                                  const float* __restrict__ beta,
                                                  float* __restrict__ bnS, float* __restrict__ bnH) {
  long tid = (long)blockIdx.x * 256 + threadIdx.x;
  if (tid >= 4L * NN) return;
  int q = (int)(tid & 3);
  int n = (int)(tid >> 2);
  float s1 = 0.f, s2 = 0.f;
  for (int t = q * 2; t < q * 2 + 2; ++t)
    for (int b = 0; b < 4; ++b) {
      const float* p = h3 + ((long)(t * 4 + b) * NN + n) * 8;
#pragma unroll
      for (int co = 0; co < 5; ++co) { float v = p[co]; s1 += v; s2 += v * v; }
    }
  s1 += __shfl_xor(s1, 1, 4); s1 += __shfl_xor(s1, 2, 4);
  s2 += __shfl_xor(s2, 1, 4); s2 += __shfl_xor(s2, 2, 4);
  if (q == 0) {
    float mean = s1 * (1.f / 160.f);
    float var = s2 * (1.f / 160.f) - mean * mean;
    float sc = gamma[n] * rsqrtf(var + 1e-5f);
    bnS[n] = sc;
    bnH[n] = beta[n] - mean * sc;
  }
}

__global__ void __launch_bounds__(256) k_bn_apply(float* __restrict__ h3,
                                                  const float* __restrict__ bnS,
                                                  const float* __restrict__ bnH) {
  long tid = (long)blockIdx.x * 256 + threadIdx.x;
  if (tid >= 32L * NN * 8) return;
  int n = (int)((tid >> 3) % NN);
  h3[tid] = fmaxf(h3[tid] * bnS[n] + bnH[n], 0.f);
}

// ---------------- PX precompute: edge-parallel, 8 lanes/node (padded rows) ----------------
__global__ void __launch_bounds__(256) k_prop5(const float* __restrict__ h3, float* __restrict__ PX,
                                               const int* __restrict__ rowptr, const EdgeP* __restrict__ epk) {
  unsigned bid = swz8(blockIdx.x, gridDim.x);
  long tid = (long)bid * 256 + threadIdx.x;
  long ng = tid >> 3;
  int eq = (int)(tid & 7);
  if (ng >= 32L * NN) return;
  int s = (int)(ng / NN), n = (int)(ng % NN);
  int beg = rowptr[n], end = rowptr[n + 1];
  const float* src = h3 + (long)s * NN * 8;
  float a0 = 0.f, a1 = 0.f, a2 = 0.f, a3 = 0.f, a4 = 0.f;
  for (int e0 = beg; e0 < end; e0 += 8) {
    int e = e0 + eq;
    int ec = min(e, end - 1);
    EdgeP ep = epk[ec];
    float w = (e < end) ? ep.w : 0.f;
    const float* row = src + ((long)ep.c) * 8;
    float4 v = *(const float4*)row;
    float v4 = row[4];
    a0 = fmaf(w, v.x, a0); a1 = fmaf(w, v.y, a1); a2 = fmaf(w, v.z, a2);
    a3 = fmaf(w, v.w, a3); a4 = fmaf(w, v4, a4);
  }
#pragma unroll
  for (int m = 1; m <= 4; m <<= 1) {
    a0 += __shfl_xor(a0, m); a1 += __shfl_xor(a1, m); a2 += __shfl_xor(a2, m);
    a3 += __shfl_xor(a3, m); a4 += __shfl_xor(a4, m);
  }
  if (eq == 0) {
    float* dst = PX + ng * 8;
    *(float4*)dst = make_float4(a0, a1, a2, a3);
    dst[4] = a4;
  }
}

// ---------------- fused GRU step kernels (edge-parallel gathers) ----------------
__global__ void __launch_bounds__(256) k_gru1(const float* __restrict__ h3, const float* __restrict__ PX,
                                              const float* __restrict__ Hp,
                                              const int* __restrict__ rowptr, const EdgeP* __restrict__ epk,
                                              const float* __restrict__ gwx, const float* __restrict__ gbx,
                                              const float* __restrict__ gwh, const float* __restrict__ gbh,
                                              float* __restrict__ Z, float* __restrict__ HR, int t) {
  __shared__ float swh[4096];
  __shared__ float swx[640];
  for (int i = threadIdx.x; i < 4096; i += 256) swh[i] = gwh[i];
  for (int i = threadIdx.x; i < 640; i += 256) swx[i] = gwx[i];
  __syncthreads();
  unsigned bid = swz8(blockIdx.x, gridDim.x);
  long tid = (long)bid * 256 + threadIdx.x;
  long ng = tid >> 5;
  int j = (int)(tid & 31);
  if (ng >= 4L * NN) return;
  int b = (int)(ng / NN), n = (int)(ng % NN);
  long hrow = ng * 32;
  long xrow = ((long)(t * 4 + b) * NN + n) * 8;
  const float* hsrc = Hp + (long)b * NN * 32;
  float hv = Hp[hrow + j];
  int eq = j >> 3, cl = j & 7;
  int beg = rowptr[n], end = rowptr[n + 1];
  float4 pa = make_float4(0.f, 0.f, 0.f, 0.f);
  for (int e0 = beg; e0 < end; e0 += 4) {
    int e = e0 + eq;
    int ec = min(e, end - 1);
    EdgeP ep = epk[ec];
    float w = (e < end) ? ep.w : 0.f;
    float4 hh = *(const float4*)(hsrc + ((long)ep.c) * 32 + cl * 4);
    pa.x = fmaf(w, hh.x, pa.x); pa.y = fmaf(w, hh.y, pa.y);
    pa.z = fmaf(w, hh.z, pa.z); pa.w = fmaf(w, hh.w, pa.w);
  }
  pa.x += __shfl_xor(pa.x, 8);  pa.y += __shfl_xor(pa.y, 8);
  pa.z += __shfl_xor(pa.z, 8);  pa.w += __shfl_xor(pa.w, 8);
  pa.x += __shfl_xor(pa.x, 16); pa.y += __shfl_xor(pa.y, 16);
  pa.z += __shfl_xor(pa.z, 16); pa.w += __shfl_xor(pa.w, 16);
  float v0 = __shfl(pa.x, j >> 2, 32);
  float v1 = __shfl(pa.y, j >> 2, 32);
  float v2 = __shfl(pa.z, j >> 2, 32);
  float v3 = __shfl(pa.w, j >> 2, 32);
  int pp = j & 3;
  float ph = pp == 0 ? v0 : pp == 1 ? v1 : pp == 2 ? v2 : v3;
  float az = gbx[j] + gbh[j];
  float ar = gbx[32 + j] + gbh[32 + j];
#pragma unroll
  for (int ci = 0; ci < 5; ++ci) {
    float xv = h3[xrow + ci], pv = PX[xrow + ci];
    az += xv * swx[ci * 32 + j] + pv * swx[160 + ci * 32 + j];
    ar += xv * swx[320 + ci * 32 + j] + pv * swx[480 + ci * 32 + j];
  }
#pragma unroll
  for (int ci = 0; ci < 32; ++ci) {
    float hb = __shfl(hv, ci, 32);
    float pb = __shfl(ph, ci, 32);
    az += hb * swh[ci * 32 + j] + pb * swh[1024 + ci * 32 + j];
    ar += hb * swh[2048 + ci * 32 + j] + pb * swh[3072 + ci * 32 + j];
  }
  float zz = 1.f / (1.f + expf(-az));
  float rr = 1.f / (1.f + expf(-ar));
  Z[hrow + j] = zz;
  HR[hrow + j] = hv * rr;
}

__global__ void __launch_bounds__(256) k_gru2(const float* __restrict__ h3, const float* __restrict__ PX,
                                              const float* __restrict__ Hp, const float* __restrict__ Z,
                                              const float* __restrict__ HR,
                                              const int* __restrict__ rowptr, const EdgeP* __restrict__ epk,
                                              const float* __restrict__ gwx, const float* __restrict__ gbx,
                                              const float* __restrict__ gwh, const float* __restrict__ gbh,
                                              const float* __restrict__ lw, const float* __restrict__ lb,
                                              float* __restrict__ Hn, float* __restrict__ logits, int t) {
  __shared__ float swh[2048];
  __shared__ float swx[320];
  for (int i = threadIdx.x; i < 2048; i += 256) swh[i] = gwh[4096 + i];
  for (int i = threadIdx.x; i < 320; i += 256) swx[i] = gwx[640 + i];
  __syncthreads();
  unsigned bid = swz8(blockIdx.x, gridDim.x);
  long tid = (long)bid * 256 + threadIdx.x;
  long ng = tid >> 5;
  int j = (int)(tid & 31);
  if (ng >= 4L * NN) return;
  int b = (int)(ng / NN), n = (int)(ng % NN);
  long hrow = ng * 32;
  long xrow = ((long)(t * 4 + b) * NN + n) * 8;
  const float* hsrc = HR + (long)b * NN * 32;
  float hrv = HR[hrow + j];
  int eq = j >> 3, cl = j & 7;
  int beg = rowptr[n], end = rowptr[n + 1];
  float4 pa = make_float4(0.f, 0.f, 0.f, 0.f);
  for (int e0 = beg; e0 < end; e0 += 4) {
    int e = e0 + eq;
    int ec = min(e, end - 1);
    EdgeP ep = epk[ec];
    float w = (e < end) ? ep.w : 0.f;
    float4 hh = *(const float4*)(hsrc + ((long)ep.c) * 32 + cl * 4);
    pa.x = fmaf(w, hh.x, pa.x); pa.y = fmaf(w, hh.y, pa.y);
    pa.z = fmaf(w, hh.z, pa.z); pa.w = fmaf(w, hh.w, pa.w);
  }
  pa.x += __shfl_xor(pa.x, 8);  pa.y += __shfl_xor(pa.y, 8);
  pa.z += __shfl_xor(pa.z, 8);  pa.w += __shfl_xor(pa.w, 8);
  pa.x += __shfl_xor(pa.x, 16); pa.y += __shfl_xor(pa.y, 16);
  pa.z += __shfl_xor(pa.z, 16); pa.w += __shfl_xor(pa.w, 16);
  float v0 = __shfl(pa.x, j >> 2, 32);
  float v1 = __shfl(pa.y, j >> 2, 32);
  float v2 = __shfl(pa.z, j >> 2, 32);
  float v3 = __shfl(pa.w, j >> 2, 32);
  int pp = j & 3;
  float phr = pp == 0 ? v0 : pp == 1 ? v1 : pp == 2 ? v2 : v3;
  float a = gbx[64 + j] + gbh[64 + j];
#pragma unroll
  for (int ci = 0; ci < 5; ++ci) {
    float xv = h3[xrow + ci], pv = PX[xrow + ci];
    a += xv * swx[ci * 32 + j] + pv * swx[160 + ci * 32 + j];
  }
#pragma unroll
  for (int ci = 0; ci < 32; ++ci) {
    float hb = __shfl(hrv, ci, 32);
    float pb = __shfl(phr, ci, 32);
    a += hb * swh[ci * 32 + j] + pb * swh[1024 + ci * 32 + j];
  }
  float zz = Z[hrow + j];
  float hn = zz * Hp[hrow + j] + (1.f - zz) * tanhf(a);
  Hn[hrow + j] = hn;
  float c = fmaxf(hn, 0.f) * lw[j];
  c += __shfl_xor(c, 16, 32);
  c += __shfl_xor(c, 8, 32);
  c += __shfl_xor(c, 4, 32);
  c += __shfl_xor(c, 2, 32);
  c += __shfl_xor(c, 1, 32);
  if (j == 0) logits[((long)b * 8 + t) * NN + n] = c + lb[0];
}

// ---------------- final log_softmax over the 8 time steps ----------------
__global__ void __launch_bounds__(256) k_logsoftmax(const float* __restrict__ logits, float* __restrict__ out) {
  long tid = (long)blockIdx.x * 256 + threadIdx.x;
  if (tid >= 4L * NN) return;
  int b = (int)(tid / NN), n = (int)(tid % NN);
  float l[8];
#pragma unroll
  for (int t = 0; t < 8; ++t) l[t] = logits[((long)b * 8 + t) * NN + n];
  float m = l[0];
#pragma unroll
  for (int t = 1; t < 8; ++t) m = fmaxf(m, l[t]);
  float s = 0.f;
#pragma unroll
  for (int t = 0; t < 8; ++t) s += expf(l[t] - m);
  float lse = m + logf(s);
#pragma unroll
  for (int t = 0; t < 8; ++t) out[((long)b * 8 + t) * NN + n] = l[t] - lse;
}

// ---------------- host orchestration ----------------
extern "C" void kernel_launch(void* const* d_in, const int* in_sizes, int n_in,
                              void* d_out, int out_size, void* d_ws, size_t ws_size,
                              hipStream_t stream) {
  const float* x     = (const float*)d_in[0];
  const int*   ei    = (const int*)d_in[1];
  const float* tc1w  = (const float*)d_in[2];
  const float* tc1b  = (const float*)d_in[3];
  const float* chebw = (const float*)d_in[4];
  const float* chebb = (const float*)d_in[5];
  const float* tc2w  = (const float*)d_in[6];
  const float* tc2b  = (const float*)d_in[7];
  const float* gam   = (const float*)d_in[8];
  const float* bet   = (const float*)d_in[9];
  const float* gwx   = (const float*)d_in[10];
  const float* gbx   = (const float*)d_in[11];
  const float* gwh   = (const float*)d_in[12];
  const float* gbh   = (const float*)d_in[13];
  const float* lw    = (const float*)d_in[14];
  const float* lb    = (const float*)d_in[15];
  float* out = (float*)d_out;
  int E = in_sizes[1] / 2;
  if (ws_size < WS_NEED) return;

  char* ws = (char*)d_ws;
  unsigned short* Xb  = (unsigned short*)(ws + O_XB);
  unsigned short* T1b = (unsigned short*)(ws + O_T1B);
  unsigned short* T2b = (unsigned short*)(ws + O_T2B);
  unsigned short* H2b = (unsigned short*)(ws + O_H2B);
  float* h3   = (float*)(ws + O_H3);
  float* PX   = (float*)(ws + O_PX);
  float* bnS  = (float*)(ws + O_BNS);
  float* bnH  = (float*)(ws + O_BNH);
  float* degf = (float*)(ws + O_DEG);
  int*   ind  = (int*)(ws + O_IND);
  int*   cur  = (int*)(ws + O_CUR);
  float* dnv  = (float*)(ws + O_DNV);
  int*   rp   = (int*)(ws + O_RP);
  EdgeP* epk  = (EdgeP*)(ws + O_EPK);
  float* lg   = (float*)(ws + O_LG);
  unsigned short* Wp = (unsigned short*)(ws + O_WP);
  float* Hp  = (float*)(ws + O_XB);
  float* Hn  = (float*)(ws + O_XB + SZ_H);
  float* Zb  = (float*)(ws + O_XB + 2 * SZ_H);
  float* HRb = (float*)(ws + O_XB + 3 * SZ_H);

  // --- graph prep + weight pack ---
  hipMemsetAsync(ws + O_DEG, 0, 240000, stream);
  unsigned gE = (unsigned)((E + 255) / 256);
  k_edge_count<<<gE, 256, 0, stream>>>(ei, E, degf, ind);
  k_dinv<<<(NN + 255) / 256, 256, 0, stream>>>(degf, dnv);
  k_scan<<<1, 1024, 0, stream>>>(ind, rp);
  k_fill<<<gE, 256, 0, stream>>>(ei, E, dnv, rp, cur, epk);
  k_wpack<<<6, 256, 0, stream>>>(chebw, Wp);

  // --- per-batch STConv pipeline ---
  unsigned g64 = (unsigned)((ROWS * 64 + 255) / 256);  // 50000
  for (int b = 0; b < 4; ++b) {
    k_tc1<<<g64, 256, 0, stream>>>(x, tc1w, tc1b, Xb, b);
    k_prop_bf<<<g64, 256, 0, stream>>>(Xb, T1b, nullptr, rp, epk);
    k_prop_bf<<<g64, 256, 0, stream>>>(T1b, T2b, Xb, rp, epk);
    k_cheb_mfma<<<(unsigned)(ROWS / 16 / 4), 256, 0, stream>>>(Xb, T1b, T2b, Wp, chebb, H2b);
    k_tc2<<<(unsigned)(((long)T2n * NN + 255) / 256), 256, 0, stream>>>(H2b, tc2w, tc2b, h3, b);
  }

  // --- BatchNorm + relu ---
  k_bn_stats<<<(4 * NN + 255) / 256, 256, 0, stream>>>(h3, gam, bet, bnS, bnH);
  k_bn_apply<<<(unsigned)((32L * NN * 8 + 255) / 256), 256, 0, stream>>>(h3, bnS, bnH);

  // --- precompute prop(Xt) for all 32 (t,b) slices ---
  k_prop5<<<(unsigned)((32L * NN * 8 + 255) / 256), 256, 0, stream>>>(h3, PX, rp, epk);

  // --- GConvGRU, 8 sequential steps (2 fused kernels each) ---
  hipMemsetAsync(Hp, 0, SZ_H, stream);
  float* hp = Hp;
  float* hn = Hn;
  unsigned gG = (unsigned)((4L * NN * 32 + 255) / 256);  // 10000
  for (int t = 0; t < 8; ++t) {
    k_gru1<<<gG, 256, 0, stream>>>(h3, PX, hp, rp, epk, gwx, gbx, gwh, gbh, Zb, HRb, t);
    k_gru2<<<gG, 256, 0, stream>>>(h3, PX, hp, Zb, HRb, rp, epk, gwx, gbx, gwh, gbh,
                                   lw, lb, hn, lg, t);
    float* tmp = hp; hp = hn; hn = tmp;
  }

  unsigned gN = (unsigned)((4L * NN + 255) / 256);
  k_logsoftmax<<<gN, 256, 0, stream>>>(lg, out);
}

// Round 12
// 2056.491 us; speedup vs baseline: 2.2840x; 1.1422x over previous
//
#include <hip/hip_runtime.h>

constexpr int BB = 4, TT = 12, NN = 20000, FIN = 2;
constexpr int HID = 64, OUTC = 5;
constexpr int FIL = 32;
constexpr int T1n = 10, T2n = 8;
constexpr int EE = 320000;
constexpr long ROWS = (long)T1n * NN;  // 200000 rows per batch

typedef __attribute__((ext_vector_type(8))) short short8v;  // 8 bf16 (4 VGPRs)
typedef __attribute__((ext_vector_type(4))) float f32x4;

struct EdgeP { int c; float w; };  // fused CSR record (8B)

// ---------------- workspace layout (bytes) ----------------
constexpr size_t SZ_B   = (size_t)ROWS * 64 * 2;             // 25,600,000 bf16 slab
constexpr size_t SZ_H3P = (size_t)T2n * BB * NN * 8 * 4;     // 20,480,000 (rows padded 5->8)
constexpr size_t O_XB  = 0;
constexpr size_t O_T1B = SZ_B;
constexpr size_t O_T2B = 2 * SZ_B;
constexpr size_t O_H2B = 3 * SZ_B;                            // bf16
constexpr size_t O_H3  = O_H2B + SZ_B;
constexpr size_t O_PX  = O_H3 + SZ_H3P;
constexpr size_t O_BNS = O_PX + SZ_H3P;
constexpr size_t O_BNH = O_BNS + 80000;
constexpr size_t O_DEG = O_BNH + 80000;
constexpr size_t O_IND = O_DEG + 80000;
constexpr size_t O_CUR = O_IND + 80000;
constexpr size_t O_DNV = O_CUR + 80000;
constexpr size_t O_RP  = O_DNV + 80000;
constexpr size_t O_EPK = O_RP + 80128;
constexpr size_t O_LG  = O_EPK + (size_t)EE * 8;
constexpr size_t O_WP  = O_LG + 2560000;
constexpr size_t WS_NEED = O_WP + 24576;
constexpr size_t SZ_H = (size_t)BB * NN * FIL * 4;            // 10,240,000 (GRU state)

// ---------------- bf16 helpers ----------------
__device__ __forceinline__ float bf2f(unsigned short u) {
  union { unsigned i; float f; } x; x.i = ((unsigned)u) << 16; return x.f;
}
__device__ __forceinline__ unsigned short f2bf(float f) {
  union { float f; unsigned i; } x; x.f = f;
  unsigned r = x.i + 0x7FFFu + ((x.i >> 16) & 1u);
  return (unsigned short)(r >> 16);
}
__device__ __forceinline__ float lo_bf(unsigned u) {
  union { unsigned i; float f; } x; x.i = u << 16; return x.f;
}
__device__ __forceinline__ float hi_bf(unsigned u) {
  union { unsigned i; float f; } x; x.i = u & 0xffff0000u; return x.f;
}

// ---------------- XCD-chunked bijective block swizzle (m204) ----------------
__device__ __forceinline__ unsigned swz8(unsigned orig, unsigned nwg) {
  unsigned q = nwg >> 3, r = nwg & 7;
  unsigned xcd = orig & 7, off = orig >> 3;
  unsigned base = (xcd < r) ? xcd * (q + 1) : r * (q + 1) + (xcd - r) * q;
  return base + off;
}

// ---------------- graph preprocessing ----------------
__global__ void __launch_bounds__(256) k_edge_count(const int* __restrict__ ei, int E,
                                                    float* __restrict__ degf, int* __restrict__ indeg) {
  int e = blockIdx.x * 256 + threadIdx.x;
  if (e >= E) return;
  int s = ei[e], d = ei[E + e];
  if (s != d) {
    atomicAdd(&degf[s], 1.0f);
    atomicAdd(&indeg[d], 1);
  }
}

__global__ void __launch_bounds__(256) k_dinv(const float* __restrict__ degf, float* __restrict__ dinv) {
  int n = blockIdx.x * 256 + threadIdx.x;
  if (n >= NN) return;
  float d = degf[n];
  dinv[n] = d > 0.f ? rsqrtf(d) : 0.f;
}

__global__ void __launch_bounds__(1024) k_scan(const int* __restrict__ indeg, int* __restrict__ rowptr) {
  __shared__ int part[1024];
  const int chunk = (NN + 1023) / 1024;
  int t = threadIdx.x;
  int beg = t * chunk, end = min(beg + chunk, NN);
  int s = 0;
  for (int i = beg; i < end; ++i) s += indeg[i];
  part[t] = s;
  __syncthreads();
  if (t == 0) {
    int run = 0;
    for (int i = 0; i < 1024; ++i) { int v = part[i]; part[i] = run; run += v; }
    rowptr[NN] = run;
  }
  __syncthreads();
  int run = part[t];
  for (int i = beg; i < end; ++i) { rowptr[i] = run; run += indeg[i]; }
}

__global__ void __launch_bounds__(256) k_fill(const int* __restrict__ ei, int E,
                                              const float* __restrict__ dinv,
                                              const int* __restrict__ rowptr,
                                              int* __restrict__ cursor,
                                              EdgeP* __restrict__ epk) {
  int e = blockIdx.x * 256 + threadIdx.x;
  if (e >= E) return;
  int s = ei[e], d = ei[E + e];
  if (s != d) {
    int p = atomicAdd(&cursor[d], 1);
    EdgeP ep; ep.c = s; ep.w = -dinv[s] * dinv[d];
    epk[rowptr[d] + p] = ep;
  }
}

// ---------------- cheb weight pack into MFMA B-fragment order (bf16) ----------------
__global__ void __launch_bounds__(256) k_wpack(const float* __restrict__ W, unsigned short* __restrict__ Wp) {
  int id = blockIdx.x * 256 + threadIdx.x;
  int f = id >> 6, l = id & 63;
  int kk = f >> 2, jt = f & 3;
  int kcheb = kk >> 1;
  int cout = jt * 16 + (l & 15);
#pragma unroll
  for (int e = 0; e < 8; ++e) {
    int cin = (kk & 1) * 32 + (l >> 4) * 8 + e;
    Wp[(size_t)f * 512 + l * 8 + e] = f2bf(W[(size_t)kcheb * 4096 + cin * 64 + cout]);
  }
}

// ---------------- temporal conv 1: (B,T,N,2) -> per-b bf16 (10,N,64) ----------------
__global__ void __launch_bounds__(256) k_tc1(const float* __restrict__ x, const float* __restrict__ W,
                                             const float* __restrict__ Bv, unsigned short* __restrict__ out, int b) {
  __shared__ float ws[1152];
  __shared__ float bs[192];
  for (int i = threadIdx.x; i < 1152; i += 256) ws[i] = W[i];
  for (int i = threadIdx.x; i < 192; i += 256) bs[i] = Bv[i];
  __syncthreads();
  long tid = (long)blockIdx.x * 256 + threadIdx.x;
  if (tid >= ROWS * 64) return;
  int co = (int)(tid & 63);
  int n  = (int)((tid >> 6) % NN);
  int to = (int)(tid / (64L * NN));
  float aP = bs[co], aQ = bs[64 + co], aR = bs[128 + co];
#pragma unroll
  for (int k = 0; k < 3; ++k) {
#pragma unroll
    for (int ci = 0; ci < 2; ++ci) {
      float xv = x[(((long)b * TT + to + k) * NN + n) * FIN + ci];
      int wi = (k * 2 + ci) * 64 + co;
      aP = fmaf(xv, ws[wi], aP);
      aQ = fmaf(xv, ws[384 + wi], aQ);
      aR = fmaf(xv, ws[768 + wi], aR);
    }
  }
  float sq = 1.f / (1.f + expf(-aQ));
  out[tid] = f2bf(fmaxf(aP * sq + aR, 0.f));
}

// ---------------- bf16 CSR propagation, edge-parallel (8 edges in flight) ----------------
__global__ void __launch_bounds__(256) k_prop_bf(const unsigned short* __restrict__ v,
                                                 unsigned short* __restrict__ out,
                                                 const unsigned short* __restrict__ xin,
                                                 const int* __restrict__ rowptr,
                                                 const EdgeP* __restrict__ epk) {
  unsigned bid = swz8(blockIdx.x, gridDim.x);
  long tid = (long)bid * 256 + threadIdx.x;
  long ng = tid >> 6;
  if (ng >= ROWS) return;
  int lane = threadIdx.x & 63;
  int eq = lane >> 3, cl = lane & 7;
  int s = (int)(ng / NN);
  int n = (int)(ng % NN);
  n = __builtin_amdgcn_readfirstlane(n);
  s = __builtin_amdgcn_readfirstlane(s);
  int beg = rowptr[n], end = rowptr[n + 1];
  const unsigned short* vs = v + (long)s * NN * 64;
  float acc[8] = {0.f, 0.f, 0.f, 0.f, 0.f, 0.f, 0.f, 0.f};
  for (int e0 = beg; e0 < end; e0 += 8) {
    int e = e0 + eq;
    int ec = min(e, end - 1);
    EdgeP ep = epk[ec];
    float w = (e < end) ? ep.w : 0.f;
    const unsigned* a = (const unsigned*)(vs + (((long)ep.c) << 6) + cl * 8);
    unsigned u0 = a[0], u1 = a[1], u2 = a[2], u3 = a[3];
    acc[0] = fmaf(w, lo_bf(u0), acc[0]); acc[1] = fmaf(w, hi_bf(u0), acc[1]);
    acc[2] = fmaf(w, lo_bf(u1), acc[2]); acc[3] = fmaf(w, hi_bf(u1), acc[3]);
    acc[4] = fmaf(w, lo_bf(u2), acc[4]); acc[5] = fmaf(w, hi_bf(u2), acc[5]);
    acc[6] = fmaf(w, lo_bf(u3), acc[6]); acc[7] = fmaf(w, hi_bf(u3), acc[7]);
  }
#pragma unroll
  for (int k = 0; k < 8; ++k) {
    acc[k] += __shfl_xor(acc[k], 8);
    acc[k] += __shfl_xor(acc[k], 16);
    acc[k] += __shfl_xor(acc[k], 32);
  }
  if (eq == 0) {
    long ob = ng * 64 + cl * 8;
    short8v o;
    if (xin) {
      const unsigned* xi = (const unsigned*)(xin + ob);
#pragma unroll
      for (int k = 0; k < 4; ++k) {
        unsigned u = xi[k];
        o[2 * k]     = (short)f2bf(2.f * acc[2 * k]     - lo_bf(u));
        o[2 * k + 1] = (short)f2bf(2.f * acc[2 * k + 1] - hi_bf(u));
      }
    } else {
#pragma unroll
      for (int k = 0; k < 8; ++k) o[k] = (short)f2bf(acc[k]);
    }
    *(short8v*)(out + ob) = o;
  }
}

// ---------------- Cheb combine via MFMA -> bf16 H2 ----------------
__global__ void __launch_bounds__(256) k_cheb_mfma(const unsigned short* __restrict__ Xb,
                                                   const unsigned short* __restrict__ T1b,
                                                   const unsigned short* __restrict__ T2b,
                                                   const unsigned short* __restrict__ Wp,
                                                   const float* __restrict__ Bv,
                                                   unsigned short* __restrict__ H2b) {
  int wid = threadIdx.x >> 6, lane = threadIdx.x & 63;
  long tile = (long)blockIdx.x * 4 + wid;
  if (tile >= ROWS / 16) return;
  int r = lane & 15, g = lane >> 4;
  short8v wf[24];
#pragma unroll
  for (int f = 0; f < 24; ++f)
    wf[f] = *(const short8v*)(Wp + (size_t)f * 512 + lane * 8);
  float bias[4];
#pragma unroll
  for (int jt = 0; jt < 4; ++jt) bias[jt] = Bv[jt * 16 + r];
  long rowbase = tile * 16;
  f32x4 acc[4];
#pragma unroll
  for (int jt = 0; jt < 4; ++jt) acc[jt] = (f32x4){0.f, 0.f, 0.f, 0.f};
  const unsigned short* srcs[3] = {Xb, T1b, T2b};
#pragma unroll
  for (int kk = 0; kk < 6; ++kk) {
    const unsigned short* S = srcs[kk >> 1];
    short8v a = *(const short8v*)(S + (rowbase + r) * 64 + (kk & 1) * 32 + g * 8);
#pragma unroll
    for (int jt = 0; jt < 4; ++jt)
      acc[jt] = __builtin_amdgcn_mfma_f32_16x16x32_bf16(a, wf[kk * 4 + jt], acc[jt], 0, 0, 0);
  }
#pragma unroll
  for (int jt = 0; jt < 4; ++jt)
#pragma unroll
    for (int reg = 0; reg < 4; ++reg) {
      int m = 4 * g + reg;
      H2b[(rowbase + m) * 64 + jt * 16 + r] = f2bf(fmaxf(acc[jt][reg] + bias[jt], 0.f));
    }
}

// ---------------- temporal conv 2: per-b bf16 (10,N,64) -> h3[t*4+b][n][8] ----------------
__global__ void __launch_bounds__(256) k_tc2(const unsigned short* __restrict__ h2b, const float* __restrict__ W,
                                             const float* __restrict__ Bv, float* __restrict__ h3, int b) {
  long tid = (long)blockIdx.x * 256 + threadIdx.x;
  if (tid >= (long)T2n * NN) return;
  int t2 = (int)(tid / NN), n = (int)(tid % NN);
  float p[5], q[5], r[5];
#pragma unroll
  for (int co = 0; co < 5; ++co) { p[co] = Bv[co]; q[co] = Bv[5 + co]; r[co] = Bv[10 + co]; }
#pragma unroll
  for (int k = 0; k < 3; ++k) {
    const unsigned short* rowp = h2b + ((long)(t2 + k) * NN + n) * 64;
    for (int c8 = 0; c8 < 8; ++c8) {
      short8v vv = *(const short8v*)(rowp + c8 * 8);
      const float* w = W + ((k * 64) + c8 * 8) * 5;
#pragma unroll
      for (int u = 0; u < 8; ++u) {
        float xv = bf2f((unsigned short)vv[u]);
#pragma unroll
        for (int co = 0; co < 5; ++co) {
          p[co] = fmaf(xv, w[u * 5 + co], p[co]);
          q[co] = fmaf(xv, w[960 + u * 5 + co], q[co]);
          r[co] = fmaf(xv, w[1920 + u * 5 + co], r[co]);
        }
      }
    }
  }
  float o[5];
#pragma unroll
  for (int co = 0; co < 5; ++co) {
    float sq = 1.f / (1.f + expf(-q[co]));
    o[co] = fmaxf(p[co] * sq + r[co], 0.f);
  }
  float4* dst = (float4*)(h3 + ((long)(t2 * 4 + b) * NN + n) * 8);
  dst[0] = make_float4(o[0], o[1], o[2], o[3]);
  dst[1] = make_float4(o[4], 0.f, 0.f, 0.f);
}

// ---------------- BatchNorm (padded rows of 8) ----------------
__global__ void __launch_bounds__(256) k_bn_stats(const float* __restrict__ h3,
                                                  const float* __restrict__ gamma,
                                                  const float* __restrict__ beta,
                                                  float* __restrict__ bnS, float* __restrict__ bnH) {
  long tid = (long)blockIdx.x * 256 + threadIdx.x;
  if (tid >= 4L * NN) return;
  int q = (int)(tid & 3);
  int n = (int)(tid >> 2);
  float s1 = 0.f, s2 = 0.f;
  for (int t = q * 2; t < q * 2 + 2; ++t)
    for (int b = 0; b < 4; ++b) {
      const float* p = h3 + ((long)(t * 4 + b) * NN + n) * 8;
#pragma unroll
      for (int co = 0; co < 5; ++co) { float v = p[co]; s1 += v; s2 += v * v; }
    }
  s1 += __shfl_xor(s1, 1, 4); s1 += __shfl_xor(s1, 2, 4);
  s2 += __shfl_xor(s2, 1, 4); s2 += __shfl_xor(s2, 2, 4);
  if (q == 0) {
    float mean = s1 * (1.f / 160.f);
    float var = s2 * (1.f / 160.f) - mean * mean;
    float sc = gamma[n] * rsqrtf(var + 1e-5f);
    bnS[n] = sc;
    bnH[n] = beta[n] - mean * sc;
  }
}

__global__ void __launch_bounds__(256) k_bn_apply(float* __restrict__ h3,
                                                  const float* __restrict__ bnS,
                                                  const float* __restrict__ bnH) {
  long tid = (long)blockIdx.x * 256 + threadIdx.x;
  if (tid >= 32L * NN * 8) return;
  int n = (int)((tid >> 3) % NN);
  h3[tid] = fmaxf(h3[tid] * bnS[n] + bnH[n], 0.f);
}

// ---------------- PX precompute: edge-parallel, 8 lanes/node (padded rows) ----------------
__global__ void __launch_bounds__(256) k_prop5(const float* __restrict__ h3, float* __restrict__ PX,
                                               const int* __restrict__ rowptr, const EdgeP* __restrict__ epk) {
  unsigned bid = swz8(blockIdx.x, gridDim.x);
  long tid = (long)bid * 256 + threadIdx.x;
  long ng = tid >> 3;
  int eq = (int)(tid & 7);
  if (ng >= 32L * NN) return;
  int s = (int)(ng / NN), n = (int)(ng % NN);
  int beg = rowptr[n], end = rowptr[n + 1];
  const float* src = h3 + (long)s * NN * 8;
  float a0 = 0.f, a1 = 0.f, a2 = 0.f, a3 = 0.f, a4 = 0.f;
  for (int e0 = beg; e0 < end; e0 += 8) {
    int e = e0 + eq;
    int ec = min(e, end - 1);
    EdgeP ep = epk[ec];
    float w = (e < end) ? ep.w : 0.f;
    const float* row = src + ((long)ep.c) * 8;
    float4 v = *(const float4*)row;
    float v4 = row[4];
    a0 = fmaf(w, v.x, a0); a1 = fmaf(w, v.y, a1); a2 = fmaf(w, v.z, a2);
    a3 = fmaf(w, v.w, a3); a4 = fmaf(w, v4, a4);
  }
#pragma unroll
  for (int m = 1; m <= 4; m <<= 1) {
    a0 += __shfl_xor(a0, m); a1 += __shfl_xor(a1, m); a2 += __shfl_xor(a2, m);
    a3 += __shfl_xor(a3, m); a4 += __shfl_xor(a4, m);
  }
  if (eq == 0) {
    float* dst = PX + ng * 8;
    *(float4*)dst = make_float4(a0, a1, a2, a3);
    dst[4] = a4;
  }
}

// ---------------- fused GRU step kernels ----------------
// Restructured matvec: weights transposed in LDS (row stride 36, b128 reads,
// 4 ci per read); h/ph staged in per-node LDS rows read via uniform-address
// b128 broadcast. Eliminates 128 ds_read_b32 + 64 ds_bpermute per thread.
__global__ void __launch_bounds__(256) k_gru1(const float* __restrict__ h3, const float* __restrict__ PX,
                                              const float* __restrict__ Hp,
                                              const int* __restrict__ rowptr, const EdgeP* __restrict__ epk,
                                              const float* __restrict__ gwx, const float* __restrict__ gbx,
                                              const float* __restrict__ gwh, const float* __restrict__ gbh,
                                              float* __restrict__ Z, float* __restrict__ HR, int t) {
  __shared__ __align__(16) float swhT[4608];  // 4 matrices x [j=32][ci stride 36]
  __shared__ float swx[640];
  __shared__ __align__(16) float h_lds[256];   // 8 nodes x 32
  __shared__ __align__(16) float ph_lds[256];
  for (int i = threadIdx.x; i < 4096; i += 256) {
    int m = i >> 10, rem = i & 1023, ci = rem >> 5, j = rem & 31;
    swhT[m * 1152 + j * 36 + ci] = gwh[i];
  }
  for (int i = threadIdx.x; i < 640; i += 256) swx[i] = gwx[i];

  unsigned bid = swz8(blockIdx.x, gridDim.x);
  long tid = (long)bid * 256 + threadIdx.x;
  long ng = tid >> 5;
  int j = (int)(tid & 31);
  int nid = (threadIdx.x >> 5);               // node slot in block (0..7)
  bool alive = (ng < 4L * NN);
  int b = 0, n = 0;
  long hrow = 0, xrow = 0;
  float hv = 0.f;
  int beg = 0, end = 0;
  if (alive) {
    b = (int)(ng / NN); n = (int)(ng % NN);
    hrow = ng * 32;
    xrow = ((long)(t * 4 + b) * NN + n) * 8;
    hv = Hp[hrow + j];
    h_lds[nid * 32 + j] = hv;
    beg = rowptr[n]; end = rowptr[n + 1];
  }
  // edge-parallel gather of ph (4 edges in flight, each lane float4 of channels)
  int eq = j >> 3, cl = j & 7;
  float4 pa = make_float4(0.f, 0.f, 0.f, 0.f);
  if (alive) {
    const float* hsrc = Hp + (long)b * NN * 32;
    for (int e0 = beg; e0 < end; e0 += 4) {
      int e = e0 + eq;
      int ec = min(e, end - 1);
      EdgeP ep = epk[ec];
      float w = (e < end) ? ep.w : 0.f;
      float4 hh = *(const float4*)(hsrc + ((long)ep.c) * 32 + cl * 4);
      pa.x = fmaf(w, hh.x, pa.x); pa.y = fmaf(w, hh.y, pa.y);
      pa.z = fmaf(w, hh.z, pa.z); pa.w = fmaf(w, hh.w, pa.w);
    }
    pa.x += __shfl_xor(pa.x, 8);  pa.y += __shfl_xor(pa.y, 8);
    pa.z += __shfl_xor(pa.z, 8);  pa.w += __shfl_xor(pa.w, 8);
    pa.x += __shfl_xor(pa.x, 16); pa.y += __shfl_xor(pa.y, 16);
    pa.z += __shfl_xor(pa.z, 16); pa.w += __shfl_xor(pa.w, 16);
    if (eq == 0)  // lane cl holds reduced channels 4*cl..4*cl+3
      *(float4*)&ph_lds[nid * 32 + cl * 4] = pa;
  }
  __syncthreads();
  if (!alive) return;

  float az = gbx[j] + gbh[j];
  float ar = gbx[32 + j] + gbh[32 + j];
#pragma unroll
  for (int ci = 0; ci < 5; ++ci) {
    float xv = h3[xrow + ci], pv = PX[xrow + ci];
    az += xv * swx[ci * 32 + j] + pv * swx[160 + ci * 32 + j];
    ar += xv * swx[320 + ci * 32 + j] + pv * swx[480 + ci * 32 + j];
  }
  const float* wbase = &swhT[j * 36];
#pragma unroll
  for (int g = 0; g < 8; ++g) {
    float4 h4 = *(const float4*)&h_lds[nid * 32 + 4 * g];   // uniform -> broadcast
    float4 p4 = *(const float4*)&ph_lds[nid * 32 + 4 * g];
    const float* wb = wbase + 4 * g;
    float4 wz0 = *(const float4*)(wb);
    float4 wz1 = *(const float4*)(wb + 1152);
    float4 wr0 = *(const float4*)(wb + 2304);
    float4 wr1 = *(const float4*)(wb + 3456);
    az += h4.x * wz0.x + h4.y * wz0.y + h4.z * wz0.z + h4.w * wz0.w
        + p4.x * wz1.x + p4.y * wz1.y + p4.z * wz1.z + p4.w * wz1.w;
    ar += h4.x * wr0.x + h4.y * wr0.y + h4.z * wr0.z + h4.w * wr0.w
        + p4.x * wr1.x + p4.y * wr1.y + p4.z * wr1.z + p4.w * wr1.w;
  }
  float zz = 1.f / (1.f + expf(-az));
  float rr = 1.f / (1.f + expf(-ar));
  Z[hrow + j] = zz;
  HR[hrow + j] = hv * rr;
}

__global__ void __launch_bounds__(256) k_gru2(const float* __restrict__ h3, const float* __restrict__ PX,
                                              const float* __restrict__ Hp, const float* __restrict__ Z,
                                              const float* __restrict__ HR,
                                              const int* __restrict__ rowptr, const EdgeP* __restrict__ epk,
                                              const float* __restrict__ gwx, const float* __restrict__ gbx,
                                              const float* __restrict__ gwh, const float* __restrict__ gbh,
                                              const float* __restrict__ lw, const float* __restrict__ lb,
                                              float* __restrict__ Hn, float* __restrict__ logits, int t) {
  __shared__ __align__(16) float swhT[2304];  // 2 matrices x [32][36]
  __shared__ float swx[320];
  __shared__ __align__(16) float h_lds[256];
  __shared__ __align__(16) float ph_lds[256];
  for (int i = threadIdx.x; i < 2048; i += 256) {
    int m = i >> 10, rem = i & 1023, ci = rem >> 5, j = rem & 31;
    swhT[m * 1152 + j * 36 + ci] = gwh[4096 + i];
  }
  for (int i = threadIdx.x; i < 320; i += 256) swx[i] = gwx[640 + i];

  unsigned bid = swz8(blockIdx.x, gridDim.x);
  long tid = (long)bid * 256 + threadIdx.x;
  long ng = tid >> 5;
  int j = (int)(tid & 31);
  int nid = (threadIdx.x >> 5);
  bool alive = (ng < 4L * NN);
  int b = 0, n = 0;
  long hrow = 0, xrow = 0;
  float hrv = 0.f;
  int beg = 0, end = 0;
  if (alive) {
    b = (int)(ng / NN); n = (int)(ng % NN);
    hrow = ng * 32;
    xrow = ((long)(t * 4 + b) * NN + n) * 8;
    hrv = HR[hrow + j];
    h_lds[nid * 32 + j] = hrv;
    beg = rowptr[n]; end = rowptr[n + 1];
  }
  int eq = j >> 3, cl = j & 7;
  float4 pa = make_float4(0.f, 0.f, 0.f, 0.f);
  if (alive) {
    const float* hsrc = HR + (long)b * NN * 32;
    for (int e0 = beg; e0 < end; e0 += 4) {
      int e = e0 + eq;
      int ec = min(e, end - 1);
      EdgeP ep = epk[ec];
      float w = (e < end) ? ep.w : 0.f;
      float4 hh = *(const float4*)(hsrc + ((long)ep.c) * 32 + cl * 4);
      pa.x = fmaf(w, hh.x, pa.x); pa.y = fmaf(w, hh.y, pa.y);
      pa.z = fmaf(w, hh.z, pa.z); pa.w = fmaf(w, hh.w, pa.w);
    }
    pa.x += __shfl_xor(pa.x, 8);  pa.y += __shfl_xor(pa.y, 8);
    pa.z += __shfl_xor(pa.z, 8);  pa.w += __shfl_xor(pa.w, 8);
    pa.x += __shfl_xor(pa.x, 16); pa.y += __shfl_xor(pa.y, 16);
    pa.z += __shfl_xor(pa.z, 16); pa.w += __shfl_xor(pa.w, 16);
    if (eq == 0)
      *(float4*)&ph_lds[nid * 32 + cl * 4] = pa;
  }
  __syncthreads();
  if (!alive) return;

  float a = gbx[64 + j] + gbh[64 + j];
#pragma unroll
  for (int ci = 0; ci < 5; ++ci) {
    float xv = h3[xrow + ci], pv = PX[xrow + ci];
    a += xv * swx[ci * 32 + j] + pv * swx[160 + ci * 32 + j];
  }
  const float* wbase = &swhT[j * 36];
#pragma unroll
  for (int g = 0; g < 8; ++g) {
    float4 h4 = *(const float4*)&h_lds[nid * 32 + 4 * g];
    float4 p4 = *(const float4*)&ph_lds[nid * 32 + 4 * g];
    const float* wb = wbase + 4 * g;
    float4 w0 = *(const float4*)(wb);
    float4 w1 = *(const float4*)(wb + 1152);
    a += h4.x * w0.x + h4.y * w0.y + h4.z * w0.z + h4.w * w0.w
       + p4.x * w1.x + p4.y * w1.y + p4.z * w1.z + p4.w * w1.w;
  }
  float zz = Z[hrow + j];
  float hn = zz * Hp[hrow + j] + (1.f - zz) * tanhf(a);
  Hn[hrow + j] = hn;
  float c = fmaxf(hn, 0.f) * lw[j];
  c += __shfl_xor(c, 16, 32);
  c += __shfl_xor(c, 8, 32);
  c += __shfl_xor(c, 4, 32);
  c += __shfl_xor(c, 2, 32);
  c += __shfl_xor(c, 1, 32);
  if (j == 0) logits[((long)b * 8 + t) * NN + n] = c + lb[0];
}

// ---------------- final log_softmax over the 8 time steps ----------------
__global__ void __launch_bounds__(256) k_logsoftmax(const float* __restrict__ logits, float* __restrict__ out) {
  long tid = (long)blockIdx.x * 256 + threadIdx.x;
  if (tid >= 4L * NN) return;
  int b = (int)(tid / NN), n = (int)(tid % NN);
  float l[8];
#pragma unroll
  for (int t = 0; t < 8; ++t) l[t] = logits[((long)b * 8 + t) * NN + n];
  float m = l[0];
#pragma unroll
  for (int t = 1; t < 8; ++t) m = fmaxf(m, l[t]);
  float s = 0.f;
#pragma unroll
  for (int t = 0; t < 8; ++t) s += expf(l[t] - m);
  float lse = m + logf(s);
#pragma unroll
  for (int t = 0; t < 8; ++t) out[((long)b * 8 + t) * NN + n] = l[t] - lse;
}

// ---------------- host orchestration ----------------
extern "C" void kernel_launch(void* const* d_in, const int* in_sizes, int n_in,
                              void* d_out, int out_size, void* d_ws, size_t ws_size,
                              hipStream_t stream) {
  const float* x     = (const float*)d_in[0];
  const int*   ei    = (const int*)d_in[1];
  const float* tc1w  = (const float*)d_in[2];
  const float* tc1b  = (const float*)d_in[3];
  const float* chebw = (const float*)d_in[4];
  const float* chebb = (const float*)d_in[5];
  const float* tc2w  = (const float*)d_in[6];
  const float* tc2b  = (const float*)d_in[7];
  const float* gam   = (const float*)d_in[8];
  const float* bet   = (const float*)d_in[9];
  const float* gwx   = (const float*)d_in[10];
  const float* gbx   = (const float*)d_in[11];
  const float* gwh   = (const float*)d_in[12];
  const float* gbh   = (const float*)d_in[13];
  const float* lw    = (const float*)d_in[14];
  const float* lb    = (const float*)d_in[15];
  float* out = (float*)d_out;
  int E = in_sizes[1] / 2;
  if (ws_size < WS_NEED) return;

  char* ws = (char*)d_ws;
  unsigned short* Xb  = (unsigned short*)(ws + O_XB);
  unsigned short* T1b = (unsigned short*)(ws + O_T1B);
  unsigned short* T2b = (unsigned short*)(ws + O_T2B);
  unsigned short* H2b = (unsigned short*)(ws + O_H2B);
  float* h3   = (float*)(ws + O_H3);
  float* PX   = (float*)(ws + O_PX);
  float* bnS  = (float*)(ws + O_BNS);
  float* bnH  = (float*)(ws + O_BNH);
  float* degf = (float*)(ws + O_DEG);
  int*   ind  = (int*)(ws + O_IND);
  int*   cur  = (int*)(ws + O_CUR);
  float* dnv  = (float*)(ws + O_DNV);
  int*   rp   = (int*)(ws + O_RP);
  EdgeP* epk  = (EdgeP*)(ws + O_EPK);
  float* lg   = (float*)(ws + O_LG);
  unsigned short* Wp = (unsigned short*)(ws + O_WP);
  float* Hp  = (float*)(ws + O_XB);
  float* Hn  = (float*)(ws + O_XB + SZ_H);
  float* Zb  = (float*)(ws + O_XB + 2 * SZ_H);
  float* HRb = (float*)(ws + O_XB + 3 * SZ_H);

  // --- graph prep + weight pack ---
  hipMemsetAsync(ws + O_DEG, 0, 240000, stream);
  unsigned gE = (unsigned)((E + 255) / 256);
  k_edge_count<<<gE, 256, 0, stream>>>(ei, E, degf, ind);
  k_dinv<<<(NN + 255) / 256, 256, 0, stream>>>(degf, dnv);
  k_scan<<<1, 1024, 0, stream>>>(ind, rp);
  k_fill<<<gE, 256, 0, stream>>>(ei, E, dnv, rp, cur, epk);
  k_wpack<<<6, 256, 0, stream>>>(chebw, Wp);

  // --- per-batch STConv pipeline ---
  unsigned g64 = (unsigned)((ROWS * 64 + 255) / 256);  // 50000
  for (int b = 0; b < 4; ++b) {
    k_tc1<<<g64, 256, 0, stream>>>(x, tc1w, tc1b, Xb, b);
    k_prop_bf<<<g64, 256, 0, stream>>>(Xb, T1b, nullptr, rp, epk);
    k_prop_bf<<<g64, 256, 0, stream>>>(T1b, T2b, Xb, rp, epk);
    k_cheb_mfma<<<(unsigned)(ROWS / 16 / 4), 256, 0, stream>>>(Xb, T1b, T2b, Wp, chebb, H2b);
    k_tc2<<<(unsigned)(((long)T2n * NN + 255) / 256), 256, 0, stream>>>(H2b, tc2w, tc2b, h3, b);
  }

  // --- BatchNorm + relu ---
  k_bn_stats<<<(4 * NN + 255) / 256, 256, 0, stream>>>(h3, gam, bet, bnS, bnH);
  k_bn_apply<<<(unsigned)((32L * NN * 8 + 255) / 256), 256, 0, stream>>>(h3, bnS, bnH);

  // --- precompute prop(Xt) for all 32 (t,b) slices ---
  k_prop5<<<(unsigned)((32L * NN * 8 + 255) / 256), 256, 0, stream>>>(h3, PX, rp, epk);

  // --- GConvGRU, 8 sequential steps (2 fused kernels each) ---
  hipMemsetAsync(Hp, 0, SZ_H, stream);
  float* hp = Hp;
  float* hn = Hn;
  unsigned gG = (unsigned)((4L * NN * 32 + 255) / 256);  // 10000
  for (int t = 0; t < 8; ++t) {
    k_gru1<<<gG, 256, 0, stream>>>(h3, PX, hp, rp, epk, gwx, gbx, gwh, gbh, Zb, HRb, t);
    k_gru2<<<gG, 256, 0, stream>>>(h3, PX, hp, Zb, HRb, rp, epk, gwx, gbx, gwh, gbh,
                                   lw, lb, hn, lg, t);
    float* tmp = hp; hp = hn; hn = tmp;
  }

  unsigned gN = (unsigned)((4L * NN + 255) / 256);
  k_logsoftmax<<<gN, 256, 0, stream>>>(lg, out);
}